// Round 3
// baseline (496.865 us; speedup 1.0000x reference)
//
#include <hip/hip_runtime.h>
#include <hip/hip_bf16.h>
#include <stdint.h>

typedef unsigned short u16;
typedef __bf16 bf16x8 __attribute__((ext_vector_type(8)));
typedef __attribute__((ext_vector_type(4))) float f32x4;
typedef __attribute__((ext_vector_type(16))) float f32x16;
typedef __attribute__((ext_vector_type(4))) unsigned short u16x4;
typedef __attribute__((ext_vector_type(4))) int i32x4;
typedef __attribute__((ext_vector_type(4))) unsigned u32x4;

#define T_ 2048

__device__ __forceinline__ u16 f2bf(float f) {
  __hip_bfloat16 h = __float2bfloat16(f);
  return __builtin_bit_cast(u16, h);
}
__device__ __forceinline__ float bf2f(u16 u) {
  __hip_bfloat16 h = __builtin_bit_cast(__hip_bfloat16, u);
  return __bfloat162float(h);
}
__device__ __forceinline__ unsigned pk2(float a, float b) {
  return (unsigned)f2bf(a) | ((unsigned)f2bf(b) << 16);
}

// ---------------- casts ----------------
__global__ __launch_bounds__(256) void cast_f32_bf16(const float* __restrict__ in,
                                                     u16* __restrict__ outp, int n) {
  int i = (blockIdx.x * 256 + threadIdx.x) * 4;
  if (i < n) {
    f32x4 v = *(const f32x4*)(in + i);
    u16x4 o;
    o.x = f2bf(v.x); o.y = f2bf(v.y); o.z = f2bf(v.z); o.w = f2bf(v.w);
    *(u16x4*)(outp + i) = o;
  }
}

// in fp32 [R][C] -> out bf16 [Cpad][R]; cols >= C write 0 (zero padding rows).
__global__ __launch_bounds__(256) void castT(const float* __restrict__ in,
                                             u16* __restrict__ outp, int R, int C) {
  __shared__ float tile[32][33];
  int tx = threadIdx.x & 31, ty = threadIdx.x >> 5;
  int r0 = blockIdx.y * 32, c0 = blockIdx.x * 32;
#pragma unroll
  for (int p = 0; p < 4; p++) {
    int rr = r0 + ty + p * 8;
    int cc = c0 + tx;
    tile[ty + p * 8][tx] = (cc < C) ? in[(size_t)rr * C + cc] : 0.f;
  }
  __syncthreads();
#pragma unroll
  for (int p = 0; p < 4; p++) {
    outp[(size_t)(c0 + ty + p * 8) * R + r0 + tx] = f2bf(tile[tx][ty + p * 8]);
  }
}

// ---------------- rmsnorm over rows ----------------
__global__ __launch_bounds__(256) void rmsnorm_rows(const u16* __restrict__ in,
                                                    u16* __restrict__ outp,
                                                    const float* __restrict__ w,
                                                    int D, int sin, int sout) {
  int r = blockIdx.x, tid = threadIdx.x;
  int wave = tid >> 6, lane = tid & 63;
  __shared__ float sred[4];
  float vals[6];
  int E = D >> 8;
  float ss = 0.f;
  for (int e = 0; e < E; e++) {
    float v = bf2f(in[(size_t)r * sin + e * 256 + tid]);
    vals[e] = v;
    ss += v * v;
  }
#pragma unroll
  for (int d = 1; d < 64; d <<= 1) ss += __shfl_xor(ss, d, 64);
  if (lane == 0) sred[wave] = ss;
  __syncthreads();
  ss = sred[0] + sred[1] + sred[2] + sred[3];
  float rr = rsqrtf(ss / (float)D + 1e-6f);
  for (int e = 0; e < E; e++)
    outp[(size_t)r * sout + e * 256 + tid] = f2bf(vals[e] * rr * w[e * 256 + tid]);
}

// ---------------- GEMM: C[M,N] = A[M,K] * Bt[N,K]^T  (bf16 in, fp32 acc) ----
// BK=64, register-prefetch double-buffer, XOR-swizzled LDS (chunk ^ (row&7)).
// K must be a multiple of 64.
__global__ __launch_bounds__(256) void gemm_bt(const u16* __restrict__ A,
                                               const u16* __restrict__ Bt,
                                               void* __restrict__ Cv,
                                               int M, int N, int K, int cf32) {
  __shared__ u16 As[128 * 64];
  __shared__ u16 Bs[128 * 64];
  const int tid = threadIdx.x;
  const int wave = tid >> 6, lane = tid & 63;
  const int m0 = blockIdx.y * 128, n0 = blockIdx.x * 128;
  const int wm = (wave >> 1) * 64, wn = (wave & 1) * 64;
  const int fr = lane & 15, fq = lane >> 4;
  f32x4 acc[4][4] = {};

  const int srow = tid >> 1;
  const int scb = (tid & 1) * 4;
  const u16* apg = A + (size_t)(m0 + srow) * K + scb * 8;
  const u16* bpg = Bt + (size_t)(n0 + srow) * K + scb * 8;
  u16* awp[4];
  u16* bwp[4];
#pragma unroll
  for (int i = 0; i < 4; i++) {
    int sw = ((scb + i) ^ (srow & 7)) << 3;
    awp[i] = As + srow * 64 + sw;
    bwp[i] = Bs + srow * 64 + sw;
  }
  const u16* ard[2][4];
  const u16* brd[2][4];
#pragma unroll
  for (int ks = 0; ks < 2; ks++)
#pragma unroll
    for (int i = 0; i < 4; i++) {
      int ra = wm + 16 * i + fr;
      ard[ks][i] = As + ra * 64 + (((fq + ks * 4) ^ (ra & 7)) << 3);
      int rb = wn + 16 * i + fr;
      brd[ks][i] = Bs + rb * 64 + (((fq + ks * 4) ^ (rb & 7)) << 3);
    }

  i32x4 areg[4], breg[4];
#pragma unroll
  for (int i = 0; i < 4; i++) {
    areg[i] = *(const i32x4*)(apg + i * 8);
    breg[i] = *(const i32x4*)(bpg + i * 8);
  }

  for (int k0 = 0; k0 < K; k0 += 64) {
    if (k0) __syncthreads();
#pragma unroll
    for (int i = 0; i < 4; i++) {
      *(i32x4*)awp[i] = areg[i];
      *(i32x4*)bwp[i] = breg[i];
    }
    __syncthreads();
    if (k0 + 64 < K) {
#pragma unroll
      for (int i = 0; i < 4; i++) {
        areg[i] = *(const i32x4*)(apg + k0 + 64 + i * 8);
        breg[i] = *(const i32x4*)(bpg + k0 + 64 + i * 8);
      }
    }
#pragma unroll
    for (int ks = 0; ks < 2; ks++) {
      bf16x8 af[4], bf[4];
#pragma unroll
      for (int i = 0; i < 4; i++) {
        af[i] = *(const bf16x8*)ard[ks][i];
        bf[i] = *(const bf16x8*)brd[ks][i];
      }
#pragma unroll
      for (int i = 0; i < 4; i++)
#pragma unroll
        for (int j = 0; j < 4; j++)
          acc[i][j] = __builtin_amdgcn_mfma_f32_16x16x32_bf16(af[i], bf[j], acc[i][j], 0, 0, 0);
    }
  }
  if (cf32) {
    float* C = (float*)Cv;
#pragma unroll
    for (int i = 0; i < 4; i++)
#pragma unroll
      for (int j = 0; j < 4; j++)
#pragma unroll
        for (int r = 0; r < 4; r++)
          C[(size_t)(m0 + wm + 16 * i + fq * 4 + r) * N + n0 + wn + 16 * j + fr] = acc[i][j][r];
  } else {
    u16* C = (u16*)Cv;
#pragma unroll
    for (int i = 0; i < 4; i++)
#pragma unroll
      for (int j = 0; j < 4; j++)
#pragma unroll
        for (int r = 0; r < 4; r++)
          C[(size_t)(m0 + wm + 16 * i + fq * 4 + r) * N + n0 + wn + 16 * j + fr] = f2bf(acc[i][j][r]);
  }
}

// ---------------- q pack: head rmsnorm + rope + 1/sqrt(192) scale ----------
__global__ __launch_bounds__(256) void qpack(const u16* __restrict__ qnr,
                                             const float* __restrict__ qhw,
                                             const float* __restrict__ fcos,
                                             const float* __restrict__ fsin,
                                             u16* __restrict__ qp) {
  int gw = blockIdx.x * 4 + (threadIdx.x >> 6);
  int lane = threadIdx.x & 63;
  int r = gw >> 4, h = gw & 15;
  int b = r >> 11, t = r & 2047;
  const float sc = 0.07216878364870323f;  // 1/sqrt(192), folded into Q
  float v0 = bf2f(qnr[(size_t)r * 3072 + h * 128 + lane]);
  float v1 = bf2f(qnr[(size_t)r * 3072 + h * 128 + 64 + lane]);
  float ss = v0 * v0 + v1 * v1;
#pragma unroll
  for (int d = 1; d < 64; d <<= 1) ss += __shfl_xor(ss, d, 64);
  float rr = rsqrtf(ss * (1.f / 128.f) + 1e-6f) * sc;
  size_t ob = ((size_t)(b * 16 + h) * 2048 + t) * 192;
  qp[ob + lane] = f2bf(v0 * rr * qhw[lane]);
  qp[ob + 64 + lane] = f2bf(v1 * rr * qhw[64 + lane]);
  if (lane < 32) {
    float a = bf2f(qnr[(size_t)r * 3072 + 2048 + h * 64 + 2 * lane]);
    float bb = bf2f(qnr[(size_t)r * 3072 + 2048 + h * 64 + 2 * lane + 1]);
    float c = fcos[t * 32 + lane], s = fsin[t * 32 + lane];
    qp[ob + 128 + 2 * lane] = f2bf((a * c - bb * s) * sc);
    qp[ob + 129 + 2 * lane] = f2bf((a * s + bb * c) * sc);
  }
}

// ---------------- kv pack ----------------
__global__ __launch_bounds__(256) void kvpack(const u16* __restrict__ kvu,
                                              const u16* __restrict__ kvr,
                                              int ks,
                                              const float* __restrict__ khw,
                                              const float* __restrict__ fcos,
                                              const float* __restrict__ fsin,
                                              u16* __restrict__ kp,
                                              u16* __restrict__ vp) {
  int h = blockIdx.x & 15, tile = blockIdx.x >> 4;
  int r0 = tile * 64;
  int b = r0 >> 11;
  int tl = tile & 31;
  int tid = threadIdx.x, wave = tid >> 6, lane = tid & 63;
  __shared__ u16 vsl[128 * 66];
  int bh = b * 16 + h;
  for (int ii = 0; ii < 16; ii++) {
    int i = wave * 16 + ii;
    int r = r0 + i;
    int t = r & 2047;
    size_t kbase = (size_t)r * 4096 + h * 256;
    float v0 = bf2f(kvu[kbase + lane]);
    float v1 = bf2f(kvu[kbase + 64 + lane]);
    float ss = v0 * v0 + v1 * v1;
#pragma unroll
    for (int d = 1; d < 64; d <<= 1) ss += __shfl_xor(ss, d, 64);
    float rr = rsqrtf(ss * (1.f / 128.f) + 1e-6f);
    size_t ob = ((size_t)bh * 2048 + t) * 192;
    kp[ob + lane] = f2bf(v0 * rr * khw[lane]);
    kp[ob + 64 + lane] = f2bf(v1 * rr * khw[64 + lane]);
    vsl[lane * 66 + i] = kvu[kbase + 128 + lane];
    vsl[(lane + 64) * 66 + i] = kvu[kbase + 192 + lane];
    if (lane < 32) {
      float a = bf2f(kvr[(size_t)r * ks + 512 + 2 * lane]);
      float bb = bf2f(kvr[(size_t)r * ks + 512 + 2 * lane + 1]);
      float c = fcos[t * 32 + lane], s = fsin[t * 32 + lane];
      kp[ob + 128 + 2 * lane] = f2bf(a * c - bb * s);
      kp[ob + 129 + 2 * lane] = f2bf(a * s + bb * c);
    }
  }
  __syncthreads();
  u16* vb = vp + ((size_t)bh * 32 + tl) * 8192;  // [128 v][64 t] tile
  for (int u = 0; u < 32; u++) {
    int e = u * 256 + tid;
    vb[e] = vsl[(e >> 6) * 66 + (e & 63)];
  }
}

// ---------------- flash attention (causal), S^T formulation ----------------
// 512 blocks, one q-block (128 rows) each; LPT ordering (qb = 15 - n>>5).
// LDS 48KB (K 32K + V 16K) -> 2 blocks/CU. P never touches LDS: after
// softmax the P fragment for PV's B-operand is assembled in-register via
// pk2 + one cross-half __shfl_xor(32) per word pair (T12-equivalent,
// direction-safe). setprio(1) wraps the MFMA clusters (T5).
__global__ __launch_bounds__(256, 2) void attn_kernel(const u16* __restrict__ Q,
                                                      const u16* __restrict__ Kp,
                                                      const u16* __restrict__ Vt,
                                                      u16* __restrict__ O) {
  __shared__ u16 Ks[64 * 256];
  __shared__ u16 Vs[128 * 64];
  const int tid = threadIdx.x;
  const int lane = tid & 63;
  const int n = blockIdx.x;
  const int qb = 15 - (n >> 5);  // LPT: heavy first
  const int bh = n & 31;
  const int l31 = lane & 31, half = lane >> 5, xr = lane & 7;
  const int b = bh >> 4, h = bh & 15;
  const int wave = tid >> 6;

  const char* kgb = (const char*)(Kp + (size_t)bh * T_ * 192);
  const char* vgb = (const char*)(Vt + (size_t)bh * 32 * 8192);
  u16* kw[6];
  u16* vw[4];
#pragma unroll
  for (int c = 0; c < 6; c++) {
    unsigned fo = c * 4096 + tid * 16;
    unsigned row = fo / 384u;
    unsigned chunk = (fo - row * 384) >> 4;
    kw[c] = Ks + row * 256 + ((chunk ^ (row & 7)) << 3);
  }
#pragma unroll
  for (int c = 0; c < 4; c++) {
    unsigned fo = c * 4096 + tid * 16;
    unsigned row = fo >> 7;
    unsigned chunk = (fo >> 4) & 7;
    vw[c] = Vs + row * 64 + ((chunk ^ (row & 7)) << 3);
  }
  const u16* krd0 = Ks + l31 * 256;
  const u16* krd1 = Ks + (32 + l31) * 256;
  const u16* vrd = Vs + l31 * 64;
  i32x4 kreg[6], vreg[4];

  const int qw0 = qb * 128 + wave * 32;
  const int qg = qw0 + l31;
  const int jmax = 2 * qb + 1;

  bf16x8 qf[12];
  {
    const u16* qbp = Q + ((size_t)bh * T_ + qg) * 192 + half * 8;
#pragma unroll
    for (int t = 0; t < 12; t++) qf[t] = *(const bf16x8*)(qbp + t * 16);
  }
  f32x16 oacc[4] = {};
  float m_i = -3.0e38f, l_i = 0.f;

#pragma unroll
  for (int c = 0; c < 6; c++) kreg[c] = *(const i32x4*)(kgb + c * 4096 + tid * 16);
#pragma unroll
  for (int c = 0; c < 4; c++) vreg[c] = *(const i32x4*)(vgb + c * 4096 + tid * 16);

  for (int j = 0; j <= jmax; j++) {
    if (j) __syncthreads();
#pragma unroll
    for (int c = 0; c < 6; c++) *(i32x4*)kw[c] = kreg[c];
#pragma unroll
    for (int c = 0; c < 4; c++) *(i32x4*)vw[c] = vreg[c];
    __syncthreads();
    if (j < jmax) {
      const char* kg = kgb + (size_t)(j + 1) * 24576;
      const char* vg = vgb + (size_t)(j + 1) * 16384;
#pragma unroll
      for (int c = 0; c < 6; c++) kreg[c] = *(const i32x4*)(kg + c * 4096 + tid * 16);
#pragma unroll
      for (int c = 0; c < 4; c++) vreg[c] = *(const i32x4*)(vg + c * 4096 + tid * 16);
    }
    if (j * 64 > qw0 + 31) continue;

    f32x16 sa[2] = {};
    __builtin_amdgcn_s_setprio(1);
#pragma unroll
    for (int t = 0; t < 12; t++) {
      int sl = ((2 * t + half) ^ xr) << 3;
      bf16x8 a0 = *(const bf16x8*)(krd0 + sl);
      bf16x8 a1 = *(const bf16x8*)(krd1 + sl);
      sa[0] = __builtin_amdgcn_mfma_f32_32x32x16_bf16(a0, qf[t], sa[0], 0, 0, 0);
      sa[1] = __builtin_amdgcn_mfma_f32_32x32x16_bf16(a1, qf[t], sa[1], 0, 0, 0);
    }
    __builtin_amdgcn_s_setprio(0);
    if (j * 64 + 63 > qw0) {
      int kb = j * 64 + 4 * half;
#pragma unroll
      for (int tt = 0; tt < 2; tt++)
#pragma unroll
        for (int r = 0; r < 16; r++) {
          int kk = kb + tt * 32 + (r & 3) + 8 * (r >> 2);
          if (kk > qg) sa[tt][r] = -3.0e38f;
        }
    }
    float mx = -3.0e38f;
#pragma unroll
    for (int r = 0; r < 16; r++) mx = fmaxf(mx, fmaxf(sa[0][r], sa[1][r]));
    mx = fmaxf(mx, __shfl_xor(mx, 32, 64));
    // defer-max: only rescale O when the running max actually grew (>8)
    if (!__all(mx <= m_i + 8.0f)) {
      float mn = fmaxf(m_i, mx);
      float al = exp2f((m_i - mn) * 1.44269504f);
      l_i *= al;
#pragma unroll
      for (int vt = 0; vt < 4; vt++)
#pragma unroll
        for (int r = 0; r < 16; r++) oacc[vt][r] *= al;
      m_i = mn;
    }
    float rs = 0.f;
#pragma unroll
    for (int tt = 0; tt < 2; tt++)
#pragma unroll
      for (int r = 0; r < 16; r++) {
        float p = exp2f((sa[tt][r] - m_i) * 1.44269504f);
        sa[tt][r] = p;
        rs += p;
      }
    rs += __shfl_xor(rs, 32, 64);
    l_i += rs;

    // ---- in-register P -> B-fragment for PV (no LDS round trip) ----
    // lane(q=l31, half) owns P at k = tt*32 + 8*qd + 4*half + i.
    // pf[t=2tt+s] needs k = tt*32 + 16s + 8*half + e (e=0..7):
    //   half=0: words0/1 = own quad 2s (A), words2/3 = partner quad 2s (A)
    //   half=1: words0/1 = partner quad 2s+1 (B), words2/3 = own quad 2s+1 (B)
    bf16x8 pf[4];
#pragma unroll
    for (int tt = 0; tt < 2; tt++)
#pragma unroll
      for (int s = 0; s < 2; s++) {
        unsigned A0 = pk2(sa[tt][8 * s + 0], sa[tt][8 * s + 1]);
        unsigned A1 = pk2(sa[tt][8 * s + 2], sa[tt][8 * s + 3]);
        unsigned B0 = pk2(sa[tt][8 * s + 4], sa[tt][8 * s + 5]);
        unsigned B1 = pk2(sa[tt][8 * s + 6], sa[tt][8 * s + 7]);
        unsigned u0 = half ? A0 : B0;
        unsigned u1 = half ? A1 : B1;
        unsigned p0 = (unsigned)__shfl_xor((int)u0, 32, 64);
        unsigned p1 = (unsigned)__shfl_xor((int)u1, 32, 64);
        u32x4 w;
        w.x = half ? p0 : A0;
        w.y = half ? p1 : A1;
        w.z = half ? B0 : p0;
        w.w = half ? B1 : p1;
        pf[2 * tt + s] = __builtin_bit_cast(bf16x8, w);
      }

    __builtin_amdgcn_s_setprio(1);
#pragma unroll
    for (int t = 0; t < 4; t++) {
#pragma unroll
      for (int vt = 0; vt < 4; vt++) {
        bf16x8 vf = *(const bf16x8*)(vrd + vt * 32 * 64 + (((2 * t + half) ^ xr) << 3));
        oacc[vt] = __builtin_amdgcn_mfma_f32_32x32x16_bf16(vf, pf[t], oacc[vt], 0, 0, 0);
      }
    }
    __builtin_amdgcn_s_setprio(0);
  }
  float inv = 1.f / l_i;
  u16* orow = O + ((size_t)(b * T_ + qg)) * 2048 + h * 128 + 4 * half;
#pragma unroll
  for (int vt = 0; vt < 4; vt++)
#pragma unroll
    for (int qd = 0; qd < 4; qd++) {
      uint2 pk;
      pk.x = pk2(oacc[vt][qd * 4 + 0] * inv, oacc[vt][qd * 4 + 1] * inv);
      pk.y = pk2(oacc[vt][qd * 4 + 2] * inv, oacc[vt][qd * 4 + 3] * inv);
      *(uint2*)(orow + vt * 32 + qd * 8) = pk;
    }
}

extern "C" void kernel_launch(void* const* d_in, const int* in_sizes, int n_in,
                              void* d_out, int out_size, void* d_ws, size_t ws_size,
                              hipStream_t stream) {
  const float* x    = (const float*)d_in[0];
  const float* fcos = (const float*)d_in[1];
  const float* fsin = (const float*)d_in[2];
  const float* wqd  = (const float*)d_in[3];
  const float* qnw  = (const float*)d_in[4];
  const float* wqun = (const float*)d_in[5];
  const float* wqur = (const float*)d_in[6];
  const float* wkvd = (const float*)d_in[7];
  const float* kvnw = (const float*)d_in[8];
  const float* wkvu = (const float*)d_in[9];
  const float* qhnw = (const float*)d_in[10];
  const float* khnw = (const float*)d_in[11];
  const float* wwo  = (const float*)d_in[12];
  float* out = (float*)d_out;
  char* ws = (char*)d_ws;

  size_t off = 0;
  auto alloc = [&](size_t elems) -> u16* {
    u16* p = (u16*)(ws + off);
    off += ((elems * 2 + 255) & ~(size_t)255);
    return p;
  };
  u16* x16   = alloc(4096ull * 2048);
  u16* bqkvd = alloc(2176ull * 2048);  // fused q_down(1536) + kv_down(640)
  u16* bqu   = alloc(3072ull * 1536);  // merged q_up
  u16* bkvu  = alloc(4096ull * 512);
  u16* bwo   = alloc(2048ull * 2048);
  u16* cqkv  = alloc(4096ull * 2176);  // fused down-proj output
  u16* cq    = alloc(4096ull * 1536);
  u16* qnr   = alloc(4096ull * 3072);
  u16* ckv   = alloc(4096ull * 512);
  u16* kvu   = alloc(4096ull * 4096);
  u16* qp    = alloc(32ull * 2048 * 192);
  u16* kp    = alloc(32ull * 2048 * 192);
  u16* vp    = alloc(32ull * 2048 * 128);
  u16* ao    = alloc(4096ull * 2048);
  if (ws_size < off) return;

  cast_f32_bf16<<<8192, 256, 0, stream>>>(x, x16, 4096 * 2048);
  castT<<<dim3(48, 64), 256, 0, stream>>>(wqd, bqkvd, 2048, 1536);
  castT<<<dim3(20, 64), 256, 0, stream>>>(wkvd, bqkvd + 1536ull * 2048, 2048, 576);
  castT<<<dim3(64, 48), 256, 0, stream>>>(wqun, bqu, 1536, 2048);
  castT<<<dim3(32, 48), 256, 0, stream>>>(wqur, bqu + 2048ull * 1536, 1536, 1024);
  castT<<<dim3(128, 16), 256, 0, stream>>>(wkvu, bkvu, 512, 4096);
  castT<<<dim3(64, 64), 256, 0, stream>>>(wwo, bwo, 2048, 2048);

  gemm_bt<<<dim3(17, 32), 256, 0, stream>>>(x16, bqkvd, cqkv, 4096, 2176, 2048, 0);
  rmsnorm_rows<<<4096, 256, 0, stream>>>(cqkv, cq, qnw, 1536, 2176, 1536);
  rmsnorm_rows<<<4096, 256, 0, stream>>>(cqkv + 1536, ckv, kvnw, 512, 2176, 512);
  gemm_bt<<<dim3(24, 32), 256, 0, stream>>>(cq, bqu, qnr, 4096, 3072, 1536, 0);
  gemm_bt<<<dim3(32, 32), 256, 0, stream>>>(ckv, bkvu, kvu, 4096, 4096, 512, 0);
  qpack<<<16384, 256, 0, stream>>>(qnr, qhnw, fcos, fsin, qp);
  kvpack<<<1024, 256, 0, stream>>>(kvu, cqkv + 1536, 2176, khnw, fcos, fsin, kp, vp);
  attn_kernel<<<512, 256, 0, stream>>>(qp, kp, vp, ao);
  gemm_bt<<<dim3(16, 32), 256, 0, stream>>>(ao, bwo, out, 4096, 2048, 2048, 1);
}

// Round 4
// 484.434 us; speedup vs baseline: 1.0257x; 1.0257x over previous
//
#include <hip/hip_runtime.h>
#include <hip/hip_bf16.h>
#include <stdint.h>

typedef unsigned short u16;
typedef __bf16 bf16x8 __attribute__((ext_vector_type(8)));
typedef __attribute__((ext_vector_type(4))) float f32x4;
typedef __attribute__((ext_vector_type(16))) float f32x16;
typedef __attribute__((ext_vector_type(4))) unsigned short u16x4;
typedef __attribute__((ext_vector_type(4))) int i32x4;

#define T_ 2048

__device__ __forceinline__ u16 f2bf(float f) {
  __hip_bfloat16 h = __float2bfloat16(f);
  return __builtin_bit_cast(u16, h);
}
__device__ __forceinline__ float bf2f(u16 u) {
  __hip_bfloat16 h = __builtin_bit_cast(__hip_bfloat16, u);
  return __bfloat162float(h);
}
__device__ __forceinline__ unsigned pk2(float a, float b) {
  return (unsigned)f2bf(a) | ((unsigned)f2bf(b) << 16);
}
__device__ __forceinline__ void gload16(const u16* g, u16* l) {
  __builtin_amdgcn_global_load_lds((const __attribute__((address_space(1))) void*)g,
                                   (__attribute__((address_space(3))) void*)l, 16, 0, 0);
}

// ---------------- casts ----------------
__global__ __launch_bounds__(256) void cast_f32_bf16(const float* __restrict__ in,
                                                     u16* __restrict__ outp, int n) {
  int i = (blockIdx.x * 256 + threadIdx.x) * 4;
  if (i < n) {
    f32x4 v = *(const f32x4*)(in + i);
    u16x4 o;
    o.x = f2bf(v.x); o.y = f2bf(v.y); o.z = f2bf(v.z); o.w = f2bf(v.w);
    *(u16x4*)(outp + i) = o;
  }
}

// in fp32 [R][C] -> out bf16 [Cpad][R]; cols >= C write 0 (zero padding rows).
__global__ __launch_bounds__(256) void castT(const float* __restrict__ in,
                                             u16* __restrict__ outp, int R, int C) {
  __shared__ float tile[32][33];
  int tx = threadIdx.x & 31, ty = threadIdx.x >> 5;
  int r0 = blockIdx.y * 32, c0 = blockIdx.x * 32;
#pragma unroll
  for (int p = 0; p < 4; p++) {
    int rr = r0 + ty + p * 8;
    int cc = c0 + tx;
    tile[ty + p * 8][tx] = (cc < C) ? in[(size_t)rr * C + cc] : 0.f;
  }
  __syncthreads();
#pragma unroll
  for (int p = 0; p < 4; p++) {
    outp[(size_t)(c0 + ty + p * 8) * R + r0 + tx] = f2bf(tile[tx][ty + p * 8]);
  }
}

// ---------------- rmsnorm over rows ----------------
__global__ __launch_bounds__(256) void rmsnorm_rows(const u16* __restrict__ in,
                                                    u16* __restrict__ outp,
                                                    const float* __restrict__ w,
                                                    int D, int sin, int sout) {
  int r = blockIdx.x, tid = threadIdx.x;
  int wave = tid >> 6, lane = tid & 63;
  __shared__ float sred[4];
  float vals[6];
  int E = D >> 8;
  float ss = 0.f;
  for (int e = 0; e < E; e++) {
    float v = bf2f(in[(size_t)r * sin + e * 256 + tid]);
    vals[e] = v;
    ss += v * v;
  }
#pragma unroll
  for (int d = 1; d < 64; d <<= 1) ss += __shfl_xor(ss, d, 64);
  if (lane == 0) sred[wave] = ss;
  __syncthreads();
  ss = sred[0] + sred[1] + sred[2] + sred[3];
  float rr = rsqrtf(ss / (float)D + 1e-6f);
  for (int e = 0; e < E; e++)
    outp[(size_t)r * sout + e * 256 + tid] = f2bf(vals[e] * rr * w[e * 256 + tid]);
}

// ---------------- GEMM: C[M,N] = A[M,K] * Bt[N,K]^T  (bf16 in, fp32 acc) ----
// BK=64, global_load_lds(16B) staging with inverse-swizzled global source:
// LDS linear (uniform base + lane*16), lane fetches chunk (lane&7)^(lane>>3)
// of row 32w+8i+(lane>>3), so LDS slot s of row r holds chunk s^(r&7) --
// identical bytes to the old XOR-swizzled ds_write layout; fragment reads
// unchanged. m97-structure 2-barrier loop. K must be a multiple of 64.
__global__ __launch_bounds__(256) void gemm_bt(const u16* __restrict__ A,
                                               const u16* __restrict__ Bt,
                                               void* __restrict__ Cv,
                                               int M, int N, int K, int cf32) {
  __shared__ u16 As[128 * 64];
  __shared__ u16 Bs[128 * 64];
  const int tid = threadIdx.x;
  const int wave = tid >> 6, lane = tid & 63;
  const int m0 = blockIdx.y * 128, n0 = blockIdx.x * 128;
  const int wm = (wave >> 1) * 64, wn = (wave & 1) * 64;
  const int fr = lane & 15, fq = lane >> 4;
  f32x4 acc[4][4] = {};

  // staging source: wave w covers rows 32w..32w+31 of each tile
  const int grow = 32 * wave + (lane >> 3);
  const int gchunk = (lane & 7) ^ (lane >> 3);
  const u16* ag = A + (size_t)(m0 + grow) * K + gchunk * 8;
  const u16* bg = Bt + (size_t)(n0 + grow) * K + gchunk * 8;
  u16* al = As + wave * 2048;  // wave-uniform LDS base; +i*512 per call
  u16* bl = Bs + wave * 2048;

  // fragment read pointers [ks][i] (swizzled: chunk c lives at slot c^(row&7))
  const u16* ard[2][4];
  const u16* brd[2][4];
#pragma unroll
  for (int ks = 0; ks < 2; ks++)
#pragma unroll
    for (int i = 0; i < 4; i++) {
      int ra = wm + 16 * i + fr;
      ard[ks][i] = As + ra * 64 + (((fq + ks * 4) ^ (ra & 7)) << 3);
      int rb = wn + 16 * i + fr;
      brd[ks][i] = Bs + rb * 64 + (((fq + ks * 4) ^ (rb & 7)) << 3);
    }

  for (int k0 = 0; k0 < K; k0 += 64) {
    if (k0) __syncthreads();
#pragma unroll
    for (int i = 0; i < 4; i++) {
      gload16(ag + k0 + (size_t)i * 8 * K, al + i * 512);
      gload16(bg + k0 + (size_t)i * 8 * K, bl + i * 512);
    }
    __syncthreads();  // compiler drains vmcnt(0) before barrier
#pragma unroll
    for (int ks = 0; ks < 2; ks++) {
      bf16x8 af[4], bf[4];
#pragma unroll
      for (int i = 0; i < 4; i++) {
        af[i] = *(const bf16x8*)ard[ks][i];
        bf[i] = *(const bf16x8*)brd[ks][i];
      }
#pragma unroll
      for (int i = 0; i < 4; i++)
#pragma unroll
        for (int j = 0; j < 4; j++)
          acc[i][j] = __builtin_amdgcn_mfma_f32_16x16x32_bf16(af[i], bf[j], acc[i][j], 0, 0, 0);
    }
  }
  if (cf32) {
    float* C = (float*)Cv;
#pragma unroll
    for (int i = 0; i < 4; i++)
#pragma unroll
      for (int j = 0; j < 4; j++)
#pragma unroll
        for (int r = 0; r < 4; r++)
          C[(size_t)(m0 + wm + 16 * i + fq * 4 + r) * N + n0 + wn + 16 * j + fr] = acc[i][j][r];
  } else {
    u16* C = (u16*)Cv;
#pragma unroll
    for (int i = 0; i < 4; i++)
#pragma unroll
      for (int j = 0; j < 4; j++)
#pragma unroll
        for (int r = 0; r < 4; r++)
          C[(size_t)(m0 + wm + 16 * i + fq * 4 + r) * N + n0 + wn + 16 * j + fr] = f2bf(acc[i][j][r]);
  }
}

// ---------------- q pack: head rmsnorm + rope + 1/sqrt(192) scale ----------
__global__ __launch_bounds__(256) void qpack(const u16* __restrict__ qnr,
                                             const float* __restrict__ qhw,
                                             const float* __restrict__ fcos,
                                             const float* __restrict__ fsin,
                                             u16* __restrict__ qp) {
  int gw = blockIdx.x * 4 + (threadIdx.x >> 6);
  int lane = threadIdx.x & 63;
  int r = gw >> 4, h = gw & 15;
  int b = r >> 11, t = r & 2047;
  const float sc = 0.07216878364870323f;  // 1/sqrt(192), folded into Q
  float v0 = bf2f(qnr[(size_t)r * 3072 + h * 128 + lane]);
  float v1 = bf2f(qnr[(size_t)r * 3072 + h * 128 + 64 + lane]);
  float ss = v0 * v0 + v1 * v1;
#pragma unroll
  for (int d = 1; d < 64; d <<= 1) ss += __shfl_xor(ss, d, 64);
  float rr = rsqrtf(ss * (1.f / 128.f) + 1e-6f) * sc;
  size_t ob = ((size_t)(b * 16 + h) * 2048 + t) * 192;
  qp[ob + lane] = f2bf(v0 * rr * qhw[lane]);
  qp[ob + 64 + lane] = f2bf(v1 * rr * qhw[64 + lane]);
  if (lane < 32) {
    float a = bf2f(qnr[(size_t)r * 3072 + 2048 + h * 64 + 2 * lane]);
    float bb = bf2f(qnr[(size_t)r * 3072 + 2048 + h * 64 + 2 * lane + 1]);
    float c = fcos[t * 32 + lane], s = fsin[t * 32 + lane];
    qp[ob + 128 + 2 * lane] = f2bf((a * c - bb * s) * sc);
    qp[ob + 129 + 2 * lane] = f2bf((a * s + bb * c) * sc);
  }
}

// ---------------- kv pack ----------------
__global__ __launch_bounds__(256) void kvpack(const u16* __restrict__ kvu,
                                              const u16* __restrict__ kvr,
                                              int ks,
                                              const float* __restrict__ khw,
                                              const float* __restrict__ fcos,
                                              const float* __restrict__ fsin,
                                              u16* __restrict__ kp,
                                              u16* __restrict__ vp) {
  int h = blockIdx.x & 15, tile = blockIdx.x >> 4;
  int r0 = tile * 64;
  int b = r0 >> 11;
  int tl = tile & 31;
  int tid = threadIdx.x, wave = tid >> 6, lane = tid & 63;
  __shared__ u16 vsl[128 * 66];
  int bh = b * 16 + h;
  for (int ii = 0; ii < 16; ii++) {
    int i = wave * 16 + ii;
    int r = r0 + i;
    int t = r & 2047;
    size_t kbase = (size_t)r * 4096 + h * 256;
    float v0 = bf2f(kvu[kbase + lane]);
    float v1 = bf2f(kvu[kbase + 64 + lane]);
    float ss = v0 * v0 + v1 * v1;
#pragma unroll
    for (int d = 1; d < 64; d <<= 1) ss += __shfl_xor(ss, d, 64);
    float rr = rsqrtf(ss * (1.f / 128.f) + 1e-6f);
    size_t ob = ((size_t)bh * 2048 + t) * 192;
    kp[ob + lane] = f2bf(v0 * rr * khw[lane]);
    kp[ob + 64 + lane] = f2bf(v1 * rr * khw[64 + lane]);
    vsl[lane * 66 + i] = kvu[kbase + 128 + lane];
    vsl[(lane + 64) * 66 + i] = kvu[kbase + 192 + lane];
    if (lane < 32) {
      float a = bf2f(kvr[(size_t)r * ks + 512 + 2 * lane]);
      float bb = bf2f(kvr[(size_t)r * ks + 512 + 2 * lane + 1]);
      float c = fcos[t * 32 + lane], s = fsin[t * 32 + lane];
      kp[ob + 128 + 2 * lane] = f2bf(a * c - bb * s);
      kp[ob + 129 + 2 * lane] = f2bf(a * s + bb * c);
    }
  }
  __syncthreads();
  u16* vb = vp + ((size_t)bh * 32 + tl) * 8192;  // [128 v][64 t] tile
  for (int u = 0; u < 32; u++) {
    int e = u * 256 + tid;
    vb[e] = vsl[(e >> 6) * 66 + (e & 63)];
  }
}

// ---------------- flash attention (causal), S^T formulation ----------------
// 512 blocks, one q-block (128 rows) each. Complementary pairing: block n
// and n+256 carry qb and 15-qb, so under round-robin XCD/CU assignment the
// two co-resident blocks on each CU sum to exactly 34 tile-steps (vs 48
// worst-case with plain LPT). LDS 64KB -> 2 blocks/CU.
__global__ __launch_bounds__(256, 2) void attn_kernel(const u16* __restrict__ Q,
                                                      const u16* __restrict__ Kp,
                                                      const u16* __restrict__ Vt,
                                                      u16* __restrict__ O) {
  __shared__ u16 Ks[64 * 256];
  __shared__ u16 Vs[128 * 64];
  __shared__ u16 Ps[4][32 * 64];
  const int tid = threadIdx.x;
  const int wave = tid >> 6, lane = tid & 63;
  const int n = blockIdx.x;
  const int qb = (n < 256) ? (15 - (n >> 5)) : ((n - 256) >> 5);
  const int bh = n & 31;
  const int l31 = lane & 31, half = lane >> 5, xr = lane & 7;
  const int b = bh >> 4, h = bh & 15;

  const char* kgb = (const char*)(Kp + (size_t)bh * T_ * 192);
  const char* vgb = (const char*)(Vt + (size_t)bh * 32 * 8192);
  u16* kw[6];
  u16* vw[4];
#pragma unroll
  for (int c = 0; c < 6; c++) {
    unsigned fo = c * 4096 + tid * 16;
    unsigned row = fo / 384u;
    unsigned chunk = (fo - row * 384) >> 4;
    kw[c] = Ks + row * 256 + ((chunk ^ (row & 7)) << 3);
  }
#pragma unroll
  for (int c = 0; c < 4; c++) {
    unsigned fo = c * 4096 + tid * 16;
    unsigned row = fo >> 7;
    unsigned chunk = (fo >> 4) & 7;
    vw[c] = Vs + row * 64 + ((chunk ^ (row & 7)) << 3);
  }
  const u16* krd0 = Ks + l31 * 256;
  const u16* krd1 = Ks + (32 + l31) * 256;
  const u16* vrd = Vs + l31 * 64;
  u16* pw = Ps[wave];
  const u16* prd = pw + l31 * 64;
  i32x4 kreg[6], vreg[4];

  const int qw0 = qb * 128 + wave * 32;
  const int qg = qw0 + l31;
  const int jmax = 2 * qb + 1;

  bf16x8 qf[12];
  {
    const u16* qbp = Q + ((size_t)bh * T_ + qg) * 192 + half * 8;
#pragma unroll
    for (int t = 0; t < 12; t++) qf[t] = *(const bf16x8*)(qbp + t * 16);
  }
  f32x16 oacc[4] = {};
  float m_i = -3.0e38f, l_i = 0.f;

#pragma unroll
  for (int c = 0; c < 6; c++) kreg[c] = *(const i32x4*)(kgb + c * 4096 + tid * 16);
#pragma unroll
  for (int c = 0; c < 4; c++) vreg[c] = *(const i32x4*)(vgb + c * 4096 + tid * 16);

  for (int j = 0; j <= jmax; j++) {
    if (j) __syncthreads();
#pragma unroll
    for (int c = 0; c < 6; c++) *(i32x4*)kw[c] = kreg[c];
#pragma unroll
    for (int c = 0; c < 4; c++) *(i32x4*)vw[c] = vreg[c];
    __syncthreads();
    if (j < jmax) {
      const char* kg = kgb + (size_t)(j + 1) * 24576;
      const char* vg = vgb + (size_t)(j + 1) * 16384;
#pragma unroll
      for (int c = 0; c < 6; c++) kreg[c] = *(const i32x4*)(kg + c * 4096 + tid * 16);
#pragma unroll
      for (int c = 0; c < 4; c++) vreg[c] = *(const i32x4*)(vg + c * 4096 + tid * 16);
    }
    if (j * 64 > qw0 + 31) continue;

    f32x16 sa[2] = {};
#pragma unroll
    for (int t = 0; t < 12; t++) {
      int sl = ((2 * t + half) ^ xr) << 3;
      bf16x8 a0 = *(const bf16x8*)(krd0 + sl);
      bf16x8 a1 = *(const bf16x8*)(krd1 + sl);
      sa[0] = __builtin_amdgcn_mfma_f32_32x32x16_bf16(a0, qf[t], sa[0], 0, 0, 0);
      sa[1] = __builtin_amdgcn_mfma_f32_32x32x16_bf16(a1, qf[t], sa[1], 0, 0, 0);
    }
    if (j * 64 + 63 > qw0) {
      int kb = j * 64 + 4 * half;
#pragma unroll
      for (int tt = 0; tt < 2; tt++)
#pragma unroll
        for (int r = 0; r < 16; r++) {
          int kk = kb + tt * 32 + (r & 3) + 8 * (r >> 2);
          if (kk > qg) sa[tt][r] = -3.0e38f;
        }
    }
    float mx = -3.0e38f;
#pragma unroll
    for (int r = 0; r < 16; r++) mx = fmaxf(mx, fmaxf(sa[0][r], sa[1][r]));
    mx = fmaxf(mx, __shfl_xor(mx, 32, 64));
    // defer-max: only rescale O when the running max actually grew (>8)
    if (!__all(mx <= m_i + 8.0f)) {
      float mn = fmaxf(m_i, mx);
      float al = exp2f((m_i - mn) * 1.44269504f);
      l_i *= al;
#pragma unroll
      for (int vt = 0; vt < 4; vt++)
#pragma unroll
        for (int r = 0; r < 16; r++) oacc[vt][r] *= al;
      m_i = mn;
    }
    float rs = 0.f;
#pragma unroll
    for (int tt = 0; tt < 2; tt++)
#pragma unroll
      for (int r = 0; r < 16; r++) {
        float p = exp2f((sa[tt][r] - m_i) * 1.44269504f);
        sa[tt][r] = p;
        rs += p;
      }
    rs += __shfl_xor(rs, 32, 64);
    l_i += rs;
#pragma unroll
    for (int tt = 0; tt < 2; tt++)
#pragma unroll
      for (int qd = 0; qd < 4; qd++) {
        uint2 pk;
        pk.x = pk2(sa[tt][qd * 4 + 0], sa[tt][qd * 4 + 1]);
        pk.y = pk2(sa[tt][qd * 4 + 2], sa[tt][qd * 4 + 3]);
        *(uint2*)(pw + l31 * 64 + (((4 * tt + qd) ^ (l31 & 7)) << 3) + half * 4) = pk;
      }
    __asm__ __volatile__("s_waitcnt lgkmcnt(0)" ::: "memory");
#pragma unroll
    for (int t = 0; t < 4; t++) {
      bf16x8 pf = *(const bf16x8*)(prd + (((2 * t + half) ^ (l31 & 7)) << 3));
#pragma unroll
      for (int vt = 0; vt < 4; vt++) {
        bf16x8 vf = *(const bf16x8*)(vrd + vt * 32 * 64 + (((2 * t + half) ^ xr) << 3));
        oacc[vt] = __builtin_amdgcn_mfma_f32_32x32x16_bf16(vf, pf, oacc[vt], 0, 0, 0);
      }
    }
  }
  float inv = 1.f / l_i;
  u16* orow = O + ((size_t)(b * T_ + qg)) * 2048 + h * 128 + 4 * half;
#pragma unroll
  for (int vt = 0; vt < 4; vt++)
#pragma unroll
    for (int qd = 0; qd < 4; qd++) {
      uint2 pk;
      pk.x = pk2(oacc[vt][qd * 4 + 0] * inv, oacc[vt][qd * 4 + 1] * inv);
      pk.y = pk2(oacc[vt][qd * 4 + 2] * inv, oacc[vt][qd * 4 + 3] * inv);
      *(uint2*)(orow + vt * 32 + qd * 8) = pk;
    }
}

extern "C" void kernel_launch(void* const* d_in, const int* in_sizes, int n_in,
                              void* d_out, int out_size, void* d_ws, size_t ws_size,
                              hipStream_t stream) {
  const float* x    = (const float*)d_in[0];
  const float* fcos = (const float*)d_in[1];
  const float* fsin = (const float*)d_in[2];
  const float* wqd  = (const float*)d_in[3];
  const float* qnw  = (const float*)d_in[4];
  const float* wqun = (const float*)d_in[5];
  const float* wqur = (const float*)d_in[6];
  const float* wkvd = (const float*)d_in[7];
  const float* kvnw = (const float*)d_in[8];
  const float* wkvu = (const float*)d_in[9];
  const float* qhnw = (const float*)d_in[10];
  const float* khnw = (const float*)d_in[11];
  const float* wwo  = (const float*)d_in[12];
  float* out = (float*)d_out;
  char* ws = (char*)d_ws;

  size_t off = 0;
  auto alloc = [&](size_t elems) -> u16* {
    u16* p = (u16*)(ws + off);
    off += ((elems * 2 + 255) & ~(size_t)255);
    return p;
  };
  u16* x16   = alloc(4096ull * 2048);
  u16* bqkvd = alloc(2176ull * 2048);  // fused q_down(1536) + kv_down(640)
  u16* bqu   = alloc(3072ull * 1536);  // merged q_up
  u16* bkvu  = alloc(4096ull * 512);
  u16* bwo   = alloc(2048ull * 2048);
  u16* cqkv  = alloc(4096ull * 2176);  // fused down-proj output
  u16* cq    = alloc(4096ull * 1536);
  u16* qnr   = alloc(4096ull * 3072);
  u16* ckv   = alloc(4096ull * 512);
  u16* kvu   = alloc(4096ull * 4096);
  u16* qp    = alloc(32ull * 2048 * 192);
  u16* kp    = alloc(32ull * 2048 * 192);
  u16* vp    = alloc(32ull * 2048 * 128);
  u16* ao    = alloc(4096ull * 2048);
  if (ws_size < off) return;

  cast_f32_bf16<<<8192, 256, 0, stream>>>(x, x16, 4096 * 2048);
  castT<<<dim3(48, 64), 256, 0, stream>>>(wqd, bqkvd, 2048, 1536);
  castT<<<dim3(20, 64), 256, 0, stream>>>(wkvd, bqkvd + 1536ull * 2048, 2048, 576);
  castT<<<dim3(64, 48), 256, 0, stream>>>(wqun, bqu, 1536, 2048);
  castT<<<dim3(32, 48), 256, 0, stream>>>(wqur, bqu + 2048ull * 1536, 1536, 1024);
  castT<<<dim3(128, 16), 256, 0, stream>>>(wkvu, bkvu, 512, 4096);
  castT<<<dim3(64, 64), 256, 0, stream>>>(wwo, bwo, 2048, 2048);

  gemm_bt<<<dim3(17, 32), 256, 0, stream>>>(x16, bqkvd, cqkv, 4096, 2176, 2048, 0);
  rmsnorm_rows<<<4096, 256, 0, stream>>>(cqkv, cq, qnw, 1536, 2176, 1536);
  rmsnorm_rows<<<4096, 256, 0, stream>>>(cqkv + 1536, ckv, kvnw, 512, 2176, 512);
  gemm_bt<<<dim3(24, 32), 256, 0, stream>>>(cq, bqu, qnr, 4096, 3072, 1536, 0);
  gemm_bt<<<dim3(32, 32), 256, 0, stream>>>(ckv, bkvu, kvu, 4096, 4096, 512, 0);
  qpack<<<16384, 256, 0, stream>>>(qnr, qhnw, fcos, fsin, qp);
  kvpack<<<1024, 256, 0, stream>>>(kvu, cqkv + 1536, 2176, khnw, fcos, fsin, kp, vp);
  attn_kernel<<<512, 256, 0, stream>>>(qp, kp, vp, ao);
  gemm_bt<<<dim3(16, 32), 256, 0, stream>>>(ao, bwo, out, 4096, 2048, 2048, 1);
}

// Round 5
// 461.132 us; speedup vs baseline: 1.0775x; 1.0505x over previous
//
#include <hip/hip_runtime.h>
#include <hip/hip_bf16.h>
#include <stdint.h>

typedef unsigned short u16;
typedef __bf16 bf16x8 __attribute__((ext_vector_type(8)));
typedef __attribute__((ext_vector_type(4))) float f32x4;
typedef __attribute__((ext_vector_type(16))) float f32x16;
typedef __attribute__((ext_vector_type(4))) unsigned short u16x4;
typedef __attribute__((ext_vector_type(4))) int i32x4;

#define T_ 2048

__device__ __forceinline__ u16 f2bf(float f) {
  __hip_bfloat16 h = __float2bfloat16(f);
  return __builtin_bit_cast(u16, h);
}
__device__ __forceinline__ float bf2f(u16 u) {
  __hip_bfloat16 h = __builtin_bit_cast(__hip_bfloat16, u);
  return __bfloat162float(h);
}
__device__ __forceinline__ unsigned pk2(float a, float b) {
  return (unsigned)f2bf(a) | ((unsigned)f2bf(b) << 16);
}
__device__ __forceinline__ void gload16(const u16* g, u16* l) {
  __builtin_amdgcn_global_load_lds((const __attribute__((address_space(1))) void*)g,
                                   (__attribute__((address_space(3))) void*)l, 16, 0, 0);
}

// ---------------- casts ----------------
__global__ __launch_bounds__(256) void cast_f32_bf16(const float* __restrict__ in,
                                                     u16* __restrict__ outp, int n) {
  int i = (blockIdx.x * 256 + threadIdx.x) * 4;
  if (i < n) {
    f32x4 v = *(const f32x4*)(in + i);
    u16x4 o;
    o.x = f2bf(v.x); o.y = f2bf(v.y); o.z = f2bf(v.z); o.w = f2bf(v.w);
    *(u16x4*)(outp + i) = o;
  }
}

// All six weight transposes in ONE dispatch (segment table) -> one ramp/tail.
// Per segment: in fp32 [R][C] -> out bf16 [Cpad][R]; cols >= C write 0.
struct CTSegs {
  const float* in[6];
  u16* out[6];
  int R[6], C[6], gx[6], start[6];
};
__global__ __launch_bounds__(256) void castT_multi(CTSegs S) {
  __shared__ float tile[32][33];
  int bid = blockIdx.x;
  int s = 0;
#pragma unroll
  for (int k = 1; k < 6; k++)
    if (bid >= S.start[k]) s = k;
  const float* in = S.in[s];
  u16* outp = S.out[s];
  const int R = S.R[s], C = S.C[s], gx = S.gx[s];
  const int local = bid - S.start[s];
  const int by = local / gx, bx = local - by * gx;
  int tx = threadIdx.x & 31, ty = threadIdx.x >> 5;
  int r0 = by * 32, c0 = bx * 32;
#pragma unroll
  for (int p = 0; p < 4; p++) {
    int rr = r0 + ty + p * 8;
    int cc = c0 + tx;
    tile[ty + p * 8][tx] = (cc < C) ? in[(size_t)rr * C + cc] : 0.f;
  }
  __syncthreads();
#pragma unroll
  for (int p = 0; p < 4; p++) {
    outp[(size_t)(c0 + ty + p * 8) * R + r0 + tx] = f2bf(tile[tx][ty + p * 8]);
  }
}

// ---------------- rmsnorm over rows ----------------
__global__ __launch_bounds__(256) void rmsnorm_rows(const u16* __restrict__ in,
                                                    u16* __restrict__ outp,
                                                    const float* __restrict__ w,
                                                    int D, int sin, int sout) {
  int r = blockIdx.x, tid = threadIdx.x;
  int wave = tid >> 6, lane = tid & 63;
  __shared__ float sred[4];
  float vals[6];
  int E = D >> 8;
  float ss = 0.f;
  for (int e = 0; e < E; e++) {
    float v = bf2f(in[(size_t)r * sin + e * 256 + tid]);
    vals[e] = v;
    ss += v * v;
  }
#pragma unroll
  for (int d = 1; d < 64; d <<= 1) ss += __shfl_xor(ss, d, 64);
  if (lane == 0) sred[wave] = ss;
  __syncthreads();
  ss = sred[0] + sred[1] + sred[2] + sred[3];
  float rr = rsqrtf(ss / (float)D + 1e-6f);
  for (int e = 0; e < E; e++)
    outp[(size_t)r * sout + e * 256 + tid] = f2bf(vals[e] * rr * w[e * 256 + tid]);
}

// ---------------- GEMM core (m97-structure, gload_lds staging) ------------
// LDS linear (uniform base + lane*16), lane fetches chunk (lane&7)^(lane>>3)
// of row 32w+8i+(lane>>3): LDS slot s of row r holds chunk s^(r&7); swizzled
// ds_read_b128 fragment reads. K must be a multiple of 64.
__device__ __forceinline__ void gemm_body(const u16* __restrict__ A,
                                          const u16* __restrict__ Bt,
                                          void* __restrict__ Cv,
                                          int M, int N, int K, int cf32,
                                          int m0, int n0, u16* As, u16* Bs) {
  const int tid = threadIdx.x;
  const int wave = tid >> 6, lane = tid & 63;
  const int wm = (wave >> 1) * 64, wn = (wave & 1) * 64;
  const int fr = lane & 15, fq = lane >> 4;
  f32x4 acc[4][4] = {};

  const int grow = 32 * wave + (lane >> 3);
  const int gchunk = (lane & 7) ^ (lane >> 3);
  const u16* ag = A + (size_t)(m0 + grow) * K + gchunk * 8;
  const u16* bg = Bt + (size_t)(n0 + grow) * K + gchunk * 8;
  u16* al = As + wave * 2048;
  u16* bl = Bs + wave * 2048;

  const u16* ard[2][4];
  const u16* brd[2][4];
#pragma unroll
  for (int ks = 0; ks < 2; ks++)
#pragma unroll
    for (int i = 0; i < 4; i++) {
      int ra = wm + 16 * i + fr;
      ard[ks][i] = As + ra * 64 + (((fq + ks * 4) ^ (ra & 7)) << 3);
      int rb = wn + 16 * i + fr;
      brd[ks][i] = Bs + rb * 64 + (((fq + ks * 4) ^ (rb & 7)) << 3);
    }

  for (int k0 = 0; k0 < K; k0 += 64) {
    if (k0) __syncthreads();
#pragma unroll
    for (int i = 0; i < 4; i++) {
      gload16(ag + k0 + (size_t)i * 8 * K, al + i * 512);
      gload16(bg + k0 + (size_t)i * 8 * K, bl + i * 512);
    }
    __syncthreads();
#pragma unroll
    for (int ks = 0; ks < 2; ks++) {
      bf16x8 af[4], bf[4];
#pragma unroll
      for (int i = 0; i < 4; i++) {
        af[i] = *(const bf16x8*)ard[ks][i];
        bf[i] = *(const bf16x8*)brd[ks][i];
      }
#pragma unroll
      for (int i = 0; i < 4; i++)
#pragma unroll
        for (int j = 0; j < 4; j++)
          acc[i][j] = __builtin_amdgcn_mfma_f32_16x16x32_bf16(af[i], bf[j], acc[i][j], 0, 0, 0);
    }
  }
  if (cf32) {
    float* C = (float*)Cv;
#pragma unroll
    for (int i = 0; i < 4; i++)
#pragma unroll
      for (int j = 0; j < 4; j++)
#pragma unroll
        for (int r = 0; r < 4; r++)
          C[(size_t)(m0 + wm + 16 * i + fq * 4 + r) * N + n0 + wn + 16 * j + fr] = acc[i][j][r];
  } else {
    u16* C = (u16*)Cv;
#pragma unroll
    for (int i = 0; i < 4; i++)
#pragma unroll
      for (int j = 0; j < 4; j++)
#pragma unroll
        for (int r = 0; r < 4; r++)
          C[(size_t)(m0 + wm + 16 * i + fq * 4 + r) * N + n0 + wn + 16 * j + fr] = f2bf(acc[i][j][r]);
  }
}

__global__ __launch_bounds__(256) void gemm_bt(const u16* __restrict__ A,
                                               const u16* __restrict__ Bt,
                                               void* __restrict__ Cv,
                                               int M, int N, int K, int cf32) {
  __shared__ u16 As[128 * 64];
  __shared__ u16 Bs[128 * 64];
  gemm_body(A, Bt, Cv, M, N, K, cf32, blockIdx.y * 128, blockIdx.x * 128, As, Bs);
}

// Two independent GEMMs fused into one dispatch: blockIdx.z selects params.
// z=0 (long-K job) dispatches first; z=1 backfills; OOB z=0 blocks exit.
__global__ __launch_bounds__(256) void gemm_bt2(const u16* __restrict__ A0,
                                                const u16* __restrict__ B0,
                                                void* __restrict__ C0,
                                                int N0, int K0, int gx0,
                                                const u16* __restrict__ A1,
                                                const u16* __restrict__ B1,
                                                void* __restrict__ C1,
                                                int N1, int K1, int gx1) {
  __shared__ u16 As[128 * 64];
  __shared__ u16 Bs[128 * 64];
  if (blockIdx.z == 0) {
    if ((int)blockIdx.x >= gx0) return;
    gemm_body(A0, B0, C0, 4096, N0, K0, 0, blockIdx.y * 128, blockIdx.x * 128, As, Bs);
  } else {
    if ((int)blockIdx.x >= gx1) return;
    gemm_body(A1, B1, C1, 4096, N1, K1, 0, blockIdx.y * 128, blockIdx.x * 128, As, Bs);
  }
}

// ---------------- q pack: head rmsnorm + rope + 1/sqrt(192) scale ----------
__global__ __launch_bounds__(256) void qpack(const u16* __restrict__ qnr,
                                             const float* __restrict__ qhw,
                                             const float* __restrict__ fcos,
                                             const float* __restrict__ fsin,
                                             u16* __restrict__ qp) {
  int gw = blockIdx.x * 4 + (threadIdx.x >> 6);
  int lane = threadIdx.x & 63;
  int r = gw >> 4, h = gw & 15;
  int b = r >> 11, t = r & 2047;
  const float sc = 0.07216878364870323f;  // 1/sqrt(192), folded into Q
  float v0 = bf2f(qnr[(size_t)r * 3072 + h * 128 + lane]);
  float v1 = bf2f(qnr[(size_t)r * 3072 + h * 128 + 64 + lane]);
  float ss = v0 * v0 + v1 * v1;
#pragma unroll
  for (int d = 1; d < 64; d <<= 1) ss += __shfl_xor(ss, d, 64);
  float rr = rsqrtf(ss * (1.f / 128.f) + 1e-6f) * sc;
  size_t ob = ((size_t)(b * 16 + h) * 2048 + t) * 192;
  qp[ob + lane] = f2bf(v0 * rr * qhw[lane]);
  qp[ob + 64 + lane] = f2bf(v1 * rr * qhw[64 + lane]);
  if (lane < 32) {
    float a = bf2f(qnr[(size_t)r * 3072 + 2048 + h * 64 + 2 * lane]);
    float bb = bf2f(qnr[(size_t)r * 3072 + 2048 + h * 64 + 2 * lane + 1]);
    float c = fcos[t * 32 + lane], s = fsin[t * 32 + lane];
    qp[ob + 128 + 2 * lane] = f2bf((a * c - bb * s) * sc);
    qp[ob + 129 + 2 * lane] = f2bf((a * s + bb * c) * sc);
  }
}

// ---------------- kv pack ----------------
__global__ __launch_bounds__(256) void kvpack(const u16* __restrict__ kvu,
                                              const u16* __restrict__ kvr,
                                              int ks,
                                              const float* __restrict__ khw,
                                              const float* __restrict__ fcos,
                                              const float* __restrict__ fsin,
                                              u16* __restrict__ kp,
                                              u16* __restrict__ vp) {
  int h = blockIdx.x & 15, tile = blockIdx.x >> 4;
  int r0 = tile * 64;
  int b = r0 >> 11;
  int tl = tile & 31;
  int tid = threadIdx.x, wave = tid >> 6, lane = tid & 63;
  __shared__ u16 vsl[128 * 66];
  int bh = b * 16 + h;
  for (int ii = 0; ii < 16; ii++) {
    int i = wave * 16 + ii;
    int r = r0 + i;
    int t = r & 2047;
    size_t kbase = (size_t)r * 4096 + h * 256;
    float v0 = bf2f(kvu[kbase + lane]);
    float v1 = bf2f(kvu[kbase + 64 + lane]);
    float ss = v0 * v0 + v1 * v1;
#pragma unroll
    for (int d = 1; d < 64; d <<= 1) ss += __shfl_xor(ss, d, 64);
    float rr = rsqrtf(ss * (1.f / 128.f) + 1e-6f);
    size_t ob = ((size_t)bh * 2048 + t) * 192;
    kp[ob + lane] = f2bf(v0 * rr * khw[lane]);
    kp[ob + 64 + lane] = f2bf(v1 * rr * khw[64 + lane]);
    vsl[lane * 66 + i] = kvu[kbase + 128 + lane];
    vsl[(lane + 64) * 66 + i] = kvu[kbase + 192 + lane];
    if (lane < 32) {
      float a = bf2f(kvr[(size_t)r * ks + 512 + 2 * lane]);
      float bb = bf2f(kvr[(size_t)r * ks + 512 + 2 * lane + 1]);
      float c = fcos[t * 32 + lane], s = fsin[t * 32 + lane];
      kp[ob + 128 + 2 * lane] = f2bf(a * c - bb * s);
      kp[ob + 129 + 2 * lane] = f2bf(a * s + bb * c);
    }
  }
  __syncthreads();
  u16* vb = vp + ((size_t)bh * 32 + tl) * 8192;  // [128 v][64 t] tile
  for (int u = 0; u < 32; u++) {
    int e = u * 256 + tid;
    vb[e] = vsl[(e >> 6) * 66 + (e & 63)];
  }
}

// ---------------- flash attention (causal), S^T formulation ----------------
// 512 blocks, one q-block (128 rows) each; complementary pairing retained.
// LDS 64KB -> 2 blocks/CU. T5: setprio(1) around the MFMA clusters only.
__global__ __launch_bounds__(256, 2) void attn_kernel(const u16* __restrict__ Q,
                                                      const u16* __restrict__ Kp,
                                                      const u16* __restrict__ Vt,
                                                      u16* __restrict__ O) {
  __shared__ u16 Ks[64 * 256];
  __shared__ u16 Vs[128 * 64];
  __shared__ u16 Ps[4][32 * 64];
  const int tid = threadIdx.x;
  const int wave = tid >> 6, lane = tid & 63;
  const int n = blockIdx.x;
  const int qb = (n < 256) ? (15 - (n >> 5)) : ((n - 256) >> 5);
  const int bh = n & 31;
  const int l31 = lane & 31, half = lane >> 5, xr = lane & 7;
  const int b = bh >> 4, h = bh & 15;

  const char* kgb = (const char*)(Kp + (size_t)bh * T_ * 192);
  const char* vgb = (const char*)(Vt + (size_t)bh * 32 * 8192);
  u16* kw[6];
  u16* vw[4];
#pragma unroll
  for (int c = 0; c < 6; c++) {
    unsigned fo = c * 4096 + tid * 16;
    unsigned row = fo / 384u;
    unsigned chunk = (fo - row * 384) >> 4;
    kw[c] = Ks + row * 256 + ((chunk ^ (row & 7)) << 3);
  }
#pragma unroll
  for (int c = 0; c < 4; c++) {
    unsigned fo = c * 4096 + tid * 16;
    unsigned row = fo >> 7;
    unsigned chunk = (fo >> 4) & 7;
    vw[c] = Vs + row * 64 + ((chunk ^ (row & 7)) << 3);
  }
  const u16* krd0 = Ks + l31 * 256;
  const u16* krd1 = Ks + (32 + l31) * 256;
  const u16* vrd = Vs + l31 * 64;
  u16* pw = Ps[wave];
  const u16* prd = pw + l31 * 64;
  i32x4 kreg[6], vreg[4];

  const int qw0 = qb * 128 + wave * 32;
  const int qg = qw0 + l31;
  const int jmax = 2 * qb + 1;

  bf16x8 qf[12];
  {
    const u16* qbp = Q + ((size_t)bh * T_ + qg) * 192 + half * 8;
#pragma unroll
    for (int t = 0; t < 12; t++) qf[t] = *(const bf16x8*)(qbp + t * 16);
  }
  f32x16 oacc[4] = {};
  float m_i = -3.0e38f, l_i = 0.f;

#pragma unroll
  for (int c = 0; c < 6; c++) kreg[c] = *(const i32x4*)(kgb + c * 4096 + tid * 16);
#pragma unroll
  for (int c = 0; c < 4; c++) vreg[c] = *(const i32x4*)(vgb + c * 4096 + tid * 16);

  for (int j = 0; j <= jmax; j++) {
    if (j) __syncthreads();
#pragma unroll
    for (int c = 0; c < 6; c++) *(i32x4*)kw[c] = kreg[c];
#pragma unroll
    for (int c = 0; c < 4; c++) *(i32x4*)vw[c] = vreg[c];
    __syncthreads();
    if (j < jmax) {
      const char* kg = kgb + (size_t)(j + 1) * 24576;
      const char* vg = vgb + (size_t)(j + 1) * 16384;
#pragma unroll
      for (int c = 0; c < 6; c++) kreg[c] = *(const i32x4*)(kg + c * 4096 + tid * 16);
#pragma unroll
      for (int c = 0; c < 4; c++) vreg[c] = *(const i32x4*)(vg + c * 4096 + tid * 16);
    }
    if (j * 64 > qw0 + 31) continue;

    f32x16 sa[2] = {};
    __builtin_amdgcn_s_setprio(1);
#pragma unroll
    for (int t = 0; t < 12; t++) {
      int sl = ((2 * t + half) ^ xr) << 3;
      bf16x8 a0 = *(const bf16x8*)(krd0 + sl);
      bf16x8 a1 = *(const bf16x8*)(krd1 + sl);
      sa[0] = __builtin_amdgcn_mfma_f32_32x32x16_bf16(a0, qf[t], sa[0], 0, 0, 0);
      sa[1] = __builtin_amdgcn_mfma_f32_32x32x16_bf16(a1, qf[t], sa[1], 0, 0, 0);
    }
    __builtin_amdgcn_s_setprio(0);
    if (j * 64 + 63 > qw0) {
      int kb = j * 64 + 4 * half;
#pragma unroll
      for (int tt = 0; tt < 2; tt++)
#pragma unroll
        for (int r = 0; r < 16; r++) {
          int kk = kb + tt * 32 + (r & 3) + 8 * (r >> 2);
          if (kk > qg) sa[tt][r] = -3.0e38f;
        }
    }
    float mx = -3.0e38f;
#pragma unroll
    for (int r = 0; r < 16; r++) mx = fmaxf(mx, fmaxf(sa[0][r], sa[1][r]));
    mx = fmaxf(mx, __shfl_xor(mx, 32, 64));
    // defer-max: only rescale O when the running max actually grew (>8)
    if (!__all(mx <= m_i + 8.0f)) {
      float mn = fmaxf(m_i, mx);
      float al = exp2f((m_i - mn) * 1.44269504f);
      l_i *= al;
#pragma unroll
      for (int vt = 0; vt < 4; vt++)
#pragma unroll
        for (int r = 0; r < 16; r++) oacc[vt][r] *= al;
      m_i = mn;
    }
    float rs = 0.f;
#pragma unroll
    for (int tt = 0; tt < 2; tt++)
#pragma unroll
      for (int r = 0; r < 16; r++) {
        float p = exp2f((sa[tt][r] - m_i) * 1.44269504f);
        sa[tt][r] = p;
        rs += p;
      }
    rs += __shfl_xor(rs, 32, 64);
    l_i += rs;
#pragma unroll
    for (int tt = 0; tt < 2; tt++)
#pragma unroll
      for (int qd = 0; qd < 4; qd++) {
        uint2 pk;
        pk.x = pk2(sa[tt][qd * 4 + 0], sa[tt][qd * 4 + 1]);
        pk.y = pk2(sa[tt][qd * 4 + 2], sa[tt][qd * 4 + 3]);
        *(uint2*)(pw + l31 * 64 + (((4 * tt + qd) ^ (l31 & 7)) << 3) + half * 4) = pk;
      }
    __asm__ __volatile__("s_waitcnt lgkmcnt(0)" ::: "memory");
    __builtin_amdgcn_s_setprio(1);
#pragma unroll
    for (int t = 0; t < 4; t++) {
      bf16x8 pf = *(const bf16x8*)(prd + (((2 * t + half) ^ (l31 & 7)) << 3));
#pragma unroll
      for (int vt = 0; vt < 4; vt++) {
        bf16x8 vf = *(const bf16x8*)(vrd + vt * 32 * 64 + (((2 * t + half) ^ xr) << 3));
        oacc[vt] = __builtin_amdgcn_mfma_f32_32x32x16_bf16(vf, pf, oacc[vt], 0, 0, 0);
      }
    }
    __builtin_amdgcn_s_setprio(0);
  }
  float inv = 1.f / l_i;
  u16* orow = O + ((size_t)(b * T_ + qg)) * 2048 + h * 128 + 4 * half;
#pragma unroll
  for (int vt = 0; vt < 4; vt++)
#pragma unroll
    for (int qd = 0; qd < 4; qd++) {
      uint2 pk;
      pk.x = pk2(oacc[vt][qd * 4 + 0] * inv, oacc[vt][qd * 4 + 1] * inv);
      pk.y = pk2(oacc[vt][qd * 4 + 2] * inv, oacc[vt][qd * 4 + 3] * inv);
      *(uint2*)(orow + vt * 32 + qd * 8) = pk;
    }
}

extern "C" void kernel_launch(void* const* d_in, const int* in_sizes, int n_in,
                              void* d_out, int out_size, void* d_ws, size_t ws_size,
                              hipStream_t stream) {
  const float* x    = (const float*)d_in[0];
  const float* fcos = (const float*)d_in[1];
  const float* fsin = (const float*)d_in[2];
  const float* wqd  = (const float*)d_in[3];
  const float* qnw  = (const float*)d_in[4];
  const float* wqun = (const float*)d_in[5];
  const float* wqur = (const float*)d_in[6];
  const float* wkvd = (const float*)d_in[7];
  const float* kvnw = (const float*)d_in[8];
  const float* wkvu = (const float*)d_in[9];
  const float* qhnw = (const float*)d_in[10];
  const float* khnw = (const float*)d_in[11];
  const float* wwo  = (const float*)d_in[12];
  float* out = (float*)d_out;
  char* ws = (char*)d_ws;

  size_t off = 0;
  auto alloc = [&](size_t elems) -> u16* {
    u16* p = (u16*)(ws + off);
    off += ((elems * 2 + 255) & ~(size_t)255);
    return p;
  };
  u16* x16   = alloc(4096ull * 2048);
  u16* bqkvd = alloc(2176ull * 2048);  // fused q_down(1536) + kv_down(640)
  u16* bqu   = alloc(3072ull * 1536);  // merged q_up
  u16* bkvu  = alloc(4096ull * 512);
  u16* bwo   = alloc(2048ull * 2048);
  u16* cqkv  = alloc(4096ull * 2176);  // fused down-proj output
  u16* cq    = alloc(4096ull * 1536);
  u16* qnr   = alloc(4096ull * 3072);
  u16* ckv   = alloc(4096ull * 512);
  u16* kvu   = alloc(4096ull * 4096);
  u16* qp    = alloc(32ull * 2048 * 192);
  u16* kp    = alloc(32ull * 2048 * 192);
  u16* vp    = alloc(32ull * 2048 * 128);
  u16* ao    = alloc(4096ull * 2048);
  if (ws_size < off) return;

  cast_f32_bf16<<<8192, 256, 0, stream>>>(x, x16, 4096 * 2048);

  // six weight transposes, one dispatch
  CTSegs S;
  S.in[0] = wqd;  S.out[0] = bqkvd;                 S.R[0] = 2048; S.C[0] = 1536; S.gx[0] = 48;
  S.in[1] = wkvd; S.out[1] = bqkvd + 1536ull * 2048; S.R[1] = 2048; S.C[1] = 576;  S.gx[1] = 20;
  S.in[2] = wqun; S.out[2] = bqu;                   S.R[2] = 1536; S.C[2] = 2048; S.gx[2] = 64;
  S.in[3] = wqur; S.out[3] = bqu + 2048ull * 1536;  S.R[3] = 1536; S.C[3] = 1024; S.gx[3] = 32;
  S.in[4] = wkvu; S.out[4] = bkvu;                  S.R[4] = 512;  S.C[4] = 4096; S.gx[4] = 128;
  S.in[5] = wwo;  S.out[5] = bwo;                   S.R[5] = 2048; S.C[5] = 2048; S.gx[5] = 64;
  int tot = 0;
  int gy[6] = {64, 64, 48, 48, 16, 64};
  for (int k = 0; k < 6; k++) { S.start[k] = tot; tot += S.gx[k] * gy[k]; }
  castT_multi<<<tot, 256, 0, stream>>>(S);

  gemm_bt<<<dim3(17, 32), 256, 0, stream>>>(x16, bqkvd, cqkv, 4096, 2176, 2048, 0);
  rmsnorm_rows<<<4096, 256, 0, stream>>>(cqkv, cq, qnw, 1536, 2176, 1536);
  rmsnorm_rows<<<4096, 256, 0, stream>>>(cqkv + 1536, ckv, kvnw, 512, 2176, 512);
  // q_up (K=1536) and kv_up (K=512) fused: long-K z=0 first, short-K backfills
  gemm_bt2<<<dim3(32, 32, 2), 256, 0, stream>>>(cq, bqu, qnr, 3072, 1536, 24,
                                                ckv, bkvu, kvu, 4096, 512, 32);
  qpack<<<16384, 256, 0, stream>>>(qnr, qhnw, fcos, fsin, qp);
  kvpack<<<1024, 256, 0, stream>>>(kvu, cqkv + 1536, 2176, khnw, fcos, fsin, kp, vp);
  attn_kernel<<<512, 256, 0, stream>>>(qp, kp, vp, ao);
  gemm_bt<<<dim3(16, 32), 256, 0, stream>>>(ao, bwo, out, 4096, 2048, 2048, 1);
}

// Round 6
// 445.287 us; speedup vs baseline: 1.1158x; 1.0356x over previous
//
#include <hip/hip_runtime.h>
#include <hip/hip_bf16.h>
#include <stdint.h>

typedef unsigned short u16;
typedef __bf16 bf16x8 __attribute__((ext_vector_type(8)));
typedef __attribute__((ext_vector_type(4))) float f32x4;
typedef __attribute__((ext_vector_type(16))) float f32x16;
typedef __attribute__((ext_vector_type(4))) unsigned short u16x4;
typedef __attribute__((ext_vector_type(4))) int i32x4;
typedef __attribute__((ext_vector_type(2))) unsigned u32x2;
typedef __attribute__((ext_vector_type(4))) unsigned u32x4;

#define T_ 2048

__device__ __forceinline__ u16 f2bf(float f) {
  __hip_bfloat16 h = __float2bfloat16(f);
  return __builtin_bit_cast(u16, h);
}
__device__ __forceinline__ float bf2f(u16 u) {
  __hip_bfloat16 h = __builtin_bit_cast(__hip_bfloat16, u);
  return __bfloat162float(h);
}
__device__ __forceinline__ unsigned pk2(float a, float b) {
  return (unsigned)f2bf(a) | ((unsigned)f2bf(b) << 16);
}
__device__ __forceinline__ void gload16(const u16* g, u16* l) {
  __builtin_amdgcn_global_load_lds((const __attribute__((address_space(1))) void*)g,
                                   (__attribute__((address_space(3))) void*)l, 16, 0, 0);
}

// ---------------- casts ----------------
__global__ __launch_bounds__(256) void cast_f32_bf16(const float* __restrict__ in,
                                                     u16* __restrict__ outp, int n) {
  int i = (blockIdx.x * 256 + threadIdx.x) * 4;
  if (i < n) {
    f32x4 v = *(const f32x4*)(in + i);
    u16x4 o;
    o.x = f2bf(v.x); o.y = f2bf(v.y); o.z = f2bf(v.z); o.w = f2bf(v.w);
    *(u16x4*)(outp + i) = o;
  }
}

// All six weight transposes in ONE dispatch (segment table) -> one ramp/tail.
struct CTSegs {
  const float* in[6];
  u16* out[6];
  int R[6], C[6], gx[6], start[6];
};
__global__ __launch_bounds__(256) void castT_multi(CTSegs S) {
  __shared__ float tile[32][33];
  int bid = blockIdx.x;
  int s = 0;
#pragma unroll
  for (int k = 1; k < 6; k++)
    if (bid >= S.start[k]) s = k;
  const float* in = S.in[s];
  u16* outp = S.out[s];
  const int R = S.R[s], C = S.C[s], gx = S.gx[s];
  const int local = bid - S.start[s];
  const int by = local / gx, bx = local - by * gx;
  int tx = threadIdx.x & 31, ty = threadIdx.x >> 5;
  int r0 = by * 32, c0 = bx * 32;
#pragma unroll
  for (int p = 0; p < 4; p++) {
    int rr = r0 + ty + p * 8;
    int cc = c0 + tx;
    tile[ty + p * 8][tx] = (cc < C) ? in[(size_t)rr * C + cc] : 0.f;
  }
  __syncthreads();
#pragma unroll
  for (int p = 0; p < 4; p++) {
    outp[(size_t)(c0 + ty + p * 8) * R + r0 + tx] = f2bf(tile[tx][ty + p * 8]);
  }
}

// ---------------- rmsnorm over rows (both norms, one dispatch) -------------
__device__ __forceinline__ void rms_body(const u16* __restrict__ in,
                                         u16* __restrict__ outp,
                                         const float* __restrict__ w,
                                         int D, int sin, int sout, int r) {
  int tid = threadIdx.x;
  int wave = tid >> 6, lane = tid & 63;
  __shared__ float sred[4];
  float vals[6];
  int E = D >> 8;
  float ss = 0.f;
  for (int e = 0; e < E; e++) {
    float v = bf2f(in[(size_t)r * sin + e * 256 + tid]);
    vals[e] = v;
    ss += v * v;
  }
#pragma unroll
  for (int d = 1; d < 64; d <<= 1) ss += __shfl_xor(ss, d, 64);
  if (lane == 0) sred[wave] = ss;
  __syncthreads();
  ss = sred[0] + sred[1] + sred[2] + sred[3];
  float rr = rsqrtf(ss / (float)D + 1e-6f);
  for (int e = 0; e < E; e++)
    outp[(size_t)r * sout + e * 256 + tid] = f2bf(vals[e] * rr * w[e * 256 + tid]);
}

__global__ __launch_bounds__(256) void rmsnorm_dual(const u16* __restrict__ cqkv,
                                                    u16* __restrict__ cq,
                                                    const float* __restrict__ qnw,
                                                    u16* __restrict__ ckv,
                                                    const float* __restrict__ kvnw) {
  int bid = blockIdx.x;
  if (bid < 4096)
    rms_body(cqkv, cq, qnw, 1536, 2176, 1536, bid);
  else
    rms_body(cqkv + 1536, ckv, kvnw, 512, 2176, 512, bid - 4096);
}

// ---------------- GEMM core (m97-structure, gload_lds staging) ------------
__device__ __forceinline__ void gemm_body(const u16* __restrict__ A,
                                          const u16* __restrict__ Bt,
                                          void* __restrict__ Cv,
                                          int M, int N, int K, int cf32,
                                          int m0, int n0, u16* As, u16* Bs) {
  const int tid = threadIdx.x;
  const int wave = tid >> 6, lane = tid & 63;
  const int wm = (wave >> 1) * 64, wn = (wave & 1) * 64;
  const int fr = lane & 15, fq = lane >> 4;
  f32x4 acc[4][4] = {};

  const int grow = 32 * wave + (lane >> 3);
  const int gchunk = (lane & 7) ^ (lane >> 3);
  const u16* ag = A + (size_t)(m0 + grow) * K + gchunk * 8;
  const u16* bg = Bt + (size_t)(n0 + grow) * K + gchunk * 8;
  u16* al = As + wave * 2048;
  u16* bl = Bs + wave * 2048;

  const u16* ard[2][4];
  const u16* brd[2][4];
#pragma unroll
  for (int ks = 0; ks < 2; ks++)
#pragma unroll
    for (int i = 0; i < 4; i++) {
      int ra = wm + 16 * i + fr;
      ard[ks][i] = As + ra * 64 + (((fq + ks * 4) ^ (ra & 7)) << 3);
      int rb = wn + 16 * i + fr;
      brd[ks][i] = Bs + rb * 64 + (((fq + ks * 4) ^ (rb & 7)) << 3);
    }

  for (int k0 = 0; k0 < K; k0 += 64) {
    if (k0) __syncthreads();
#pragma unroll
    for (int i = 0; i < 4; i++) {
      gload16(ag + k0 + (size_t)i * 8 * K, al + i * 512);
      gload16(bg + k0 + (size_t)i * 8 * K, bl + i * 512);
    }
    __syncthreads();
#pragma unroll
    for (int ks = 0; ks < 2; ks++) {
      bf16x8 af[4], bf[4];
#pragma unroll
      for (int i = 0; i < 4; i++) {
        af[i] = *(const bf16x8*)ard[ks][i];
        bf[i] = *(const bf16x8*)brd[ks][i];
      }
#pragma unroll
      for (int i = 0; i < 4; i++)
#pragma unroll
        for (int j = 0; j < 4; j++)
          acc[i][j] = __builtin_amdgcn_mfma_f32_16x16x32_bf16(af[i], bf[j], acc[i][j], 0, 0, 0);
    }
  }
  if (cf32) {
    float* C = (float*)Cv;
#pragma unroll
    for (int i = 0; i < 4; i++)
#pragma unroll
      for (int j = 0; j < 4; j++)
#pragma unroll
        for (int r = 0; r < 4; r++)
          C[(size_t)(m0 + wm + 16 * i + fq * 4 + r) * N + n0 + wn + 16 * j + fr] = acc[i][j][r];
  } else {
    u16* C = (u16*)Cv;
#pragma unroll
    for (int i = 0; i < 4; i++)
#pragma unroll
      for (int j = 0; j < 4; j++)
#pragma unroll
        for (int r = 0; r < 4; r++)
          C[(size_t)(m0 + wm + 16 * i + fq * 4 + r) * N + n0 + wn + 16 * j + fr] = f2bf(acc[i][j][r]);
  }
}

__global__ __launch_bounds__(256) void gemm_bt(const u16* __restrict__ A,
                                               const u16* __restrict__ Bt,
                                               void* __restrict__ Cv,
                                               int M, int N, int K, int cf32) {
  __shared__ u16 As[128 * 64];
  __shared__ u16 Bs[128 * 64];
  gemm_body(A, Bt, Cv, M, N, K, cf32, blockIdx.y * 128, blockIdx.x * 128, As, Bs);
}

// Two independent GEMMs fused into one dispatch: blockIdx.z selects params.
__global__ __launch_bounds__(256) void gemm_bt2(const u16* __restrict__ A0,
                                                const u16* __restrict__ B0,
                                                void* __restrict__ C0,
                                                int N0, int K0, int gx0,
                                                const u16* __restrict__ A1,
                                                const u16* __restrict__ B1,
                                                void* __restrict__ C1,
                                                int N1, int K1, int gx1) {
  __shared__ u16 As[128 * 64];
  __shared__ u16 Bs[128 * 64];
  if (blockIdx.z == 0) {
    if ((int)blockIdx.x >= gx0) return;
    gemm_body(A0, B0, C0, 4096, N0, K0, 0, blockIdx.y * 128, blockIdx.x * 128, As, Bs);
  } else {
    if ((int)blockIdx.x >= gx1) return;
    gemm_body(A1, B1, C1, 4096, N1, K1, 0, blockIdx.y * 128, blockIdx.x * 128, As, Bs);
  }
}

// ------------- q pack + kv pack fused into one dispatch --------------------
__global__ __launch_bounds__(256) void pack_dual(const u16* __restrict__ qnr,
                                                 const float* __restrict__ qhw,
                                                 const float* __restrict__ fcos,
                                                 const float* __restrict__ fsin,
                                                 u16* __restrict__ qp,
                                                 const u16* __restrict__ kvu,
                                                 const u16* __restrict__ kvr,
                                                 const float* __restrict__ khw,
                                                 u16* __restrict__ kp,
                                                 u16* __restrict__ vp) {
  __shared__ u16 vsl[128 * 66];
  int bid = blockIdx.x;
  if (bid < 16384) {
    // ---- qpack: head rmsnorm + rope + 1/sqrt(192) scale ----
    int gw = bid * 4 + (threadIdx.x >> 6);
    int lane = threadIdx.x & 63;
    int r = gw >> 4, h = gw & 15;
    int b = r >> 11, t = r & 2047;
    const float sc = 0.07216878364870323f;  // 1/sqrt(192), folded into Q
    float v0 = bf2f(qnr[(size_t)r * 3072 + h * 128 + lane]);
    float v1 = bf2f(qnr[(size_t)r * 3072 + h * 128 + 64 + lane]);
    float ss = v0 * v0 + v1 * v1;
#pragma unroll
    for (int d = 1; d < 64; d <<= 1) ss += __shfl_xor(ss, d, 64);
    float rr = rsqrtf(ss * (1.f / 128.f) + 1e-6f) * sc;
    size_t ob = ((size_t)(b * 16 + h) * 2048 + t) * 192;
    qp[ob + lane] = f2bf(v0 * rr * qhw[lane]);
    qp[ob + 64 + lane] = f2bf(v1 * rr * qhw[64 + lane]);
    if (lane < 32) {
      float a = bf2f(qnr[(size_t)r * 3072 + 2048 + h * 64 + 2 * lane]);
      float bb = bf2f(qnr[(size_t)r * 3072 + 2048 + h * 64 + 2 * lane + 1]);
      float c = fcos[t * 32 + lane], s = fsin[t * 32 + lane];
      qp[ob + 128 + 2 * lane] = f2bf((a * c - bb * s) * sc);
      qp[ob + 129 + 2 * lane] = f2bf((a * s + bb * c) * sc);
    }
  } else {
    // ---- kvpack ----
    int q = bid - 16384;
    int h = q & 15, tile = q >> 4;
    int r0 = tile * 64;
    int b = r0 >> 11;
    int tl = tile & 31;
    int tid = threadIdx.x, wave = tid >> 6, lane = tid & 63;
    int bh = b * 16 + h;
    for (int ii = 0; ii < 16; ii++) {
      int i = wave * 16 + ii;
      int r = r0 + i;
      int t = r & 2047;
      size_t kbase = (size_t)r * 4096 + h * 256;
      float v0 = bf2f(kvu[kbase + lane]);
      float v1 = bf2f(kvu[kbase + 64 + lane]);
      float ss = v0 * v0 + v1 * v1;
#pragma unroll
      for (int d = 1; d < 64; d <<= 1) ss += __shfl_xor(ss, d, 64);
      float rr = rsqrtf(ss * (1.f / 128.f) + 1e-6f);
      size_t ob = ((size_t)bh * 2048 + t) * 192;
      kp[ob + lane] = f2bf(v0 * rr * khw[lane]);
      kp[ob + 64 + lane] = f2bf(v1 * rr * khw[64 + lane]);
      vsl[lane * 66 + i] = kvu[kbase + 128 + lane];
      vsl[(lane + 64) * 66 + i] = kvu[kbase + 192 + lane];
      if (lane < 32) {
        float a = bf2f(kvr[(size_t)r * 2176 + 512 + 2 * lane]);
        float bb = bf2f(kvr[(size_t)r * 2176 + 512 + 2 * lane + 1]);
        float c = fcos[t * 32 + lane], s = fsin[t * 32 + lane];
        kp[ob + 128 + 2 * lane] = f2bf(a * c - bb * s);
        kp[ob + 129 + 2 * lane] = f2bf(a * s + bb * c);
      }
    }
    __syncthreads();
    u16* vb = vp + ((size_t)bh * 32 + tl) * 8192;  // [128 v][64 t] tile
    for (int u = 0; u < 32; u++) {
      int e = u * 256 + tid;
      vb[e] = vsl[(e >> 6) * 66 + (e & 63)];
    }
  }
}

// ---------------- flash attention (causal), S^T formulation ----------------
// 512 blocks, one q-block (128 rows) each; complementary pairing.
// LDS 48KB (K 32K + V 16K). P never touches LDS: after softmax the PV
// B-fragment is assembled in-register with v_permlane32_swap (T12):
//   (w0,w2) = swap(X0,Y0); (w1,w3) = swap(X1,Y1)
// where X* = packed quad-lo words, Y* = quad-hi words — exact byte match
// to the old Ps round-trip, zero DS ops, zero selects.
__global__ __launch_bounds__(256, 2) void attn_kernel(const u16* __restrict__ Q,
                                                      const u16* __restrict__ Kp,
                                                      const u16* __restrict__ Vt,
                                                      u16* __restrict__ O) {
  __shared__ u16 Ks[64 * 256];
  __shared__ u16 Vs[128 * 64];
  const int tid = threadIdx.x;
  const int wave = tid >> 6, lane = tid & 63;
  const int n = blockIdx.x;
  const int qb = (n < 256) ? (15 - (n >> 5)) : ((n - 256) >> 5);
  const int bh = n & 31;
  const int l31 = lane & 31, half = lane >> 5, xr = lane & 7;
  const int b = bh >> 4, h = bh & 15;

  const char* kgb = (const char*)(Kp + (size_t)bh * T_ * 192);
  const char* vgb = (const char*)(Vt + (size_t)bh * 32 * 8192);
  u16* kw[6];
  u16* vw[4];
#pragma unroll
  for (int c = 0; c < 6; c++) {
    unsigned fo = c * 4096 + tid * 16;
    unsigned row = fo / 384u;
    unsigned chunk = (fo - row * 384) >> 4;
    kw[c] = Ks + row * 256 + ((chunk ^ (row & 7)) << 3);
  }
#pragma unroll
  for (int c = 0; c < 4; c++) {
    unsigned fo = c * 4096 + tid * 16;
    unsigned row = fo >> 7;
    unsigned chunk = (fo >> 4) & 7;
    vw[c] = Vs + row * 64 + ((chunk ^ (row & 7)) << 3);
  }
  const u16* krd0 = Ks + l31 * 256;
  const u16* krd1 = Ks + (32 + l31) * 256;
  const u16* vrd = Vs + l31 * 64;
  i32x4 kreg[6], vreg[4];

  const int qw0 = qb * 128 + wave * 32;
  const int qg = qw0 + l31;
  const int jmax = 2 * qb + 1;

  bf16x8 qf[12];
  {
    const u16* qbp = Q + ((size_t)bh * T_ + qg) * 192 + half * 8;
#pragma unroll
    for (int t = 0; t < 12; t++) qf[t] = *(const bf16x8*)(qbp + t * 16);
  }
  f32x16 oacc[4] = {};
  float m_i = -3.0e38f, l_i = 0.f;

#pragma unroll
  for (int c = 0; c < 6; c++) kreg[c] = *(const i32x4*)(kgb + c * 4096 + tid * 16);
#pragma unroll
  for (int c = 0; c < 4; c++) vreg[c] = *(const i32x4*)(vgb + c * 4096 + tid * 16);

  for (int j = 0; j <= jmax; j++) {
    if (j) __syncthreads();
#pragma unroll
    for (int c = 0; c < 6; c++) *(i32x4*)kw[c] = kreg[c];
#pragma unroll
    for (int c = 0; c < 4; c++) *(i32x4*)vw[c] = vreg[c];
    __syncthreads();
    if (j < jmax) {
      const char* kg = kgb + (size_t)(j + 1) * 24576;
      const char* vg = vgb + (size_t)(j + 1) * 16384;
#pragma unroll
      for (int c = 0; c < 6; c++) kreg[c] = *(const i32x4*)(kg + c * 4096 + tid * 16);
#pragma unroll
      for (int c = 0; c < 4; c++) vreg[c] = *(const i32x4*)(vg + c * 4096 + tid * 16);
    }
    if (j * 64 > qw0 + 31) continue;

    f32x16 sa[2] = {};
    __builtin_amdgcn_s_setprio(1);
#pragma unroll
    for (int t = 0; t < 12; t++) {
      int sl = ((2 * t + half) ^ xr) << 3;
      bf16x8 a0 = *(const bf16x8*)(krd0 + sl);
      bf16x8 a1 = *(const bf16x8*)(krd1 + sl);
      sa[0] = __builtin_amdgcn_mfma_f32_32x32x16_bf16(a0, qf[t], sa[0], 0, 0, 0);
      sa[1] = __builtin_amdgcn_mfma_f32_32x32x16_bf16(a1, qf[t], sa[1], 0, 0, 0);
    }
    __builtin_amdgcn_s_setprio(0);
    if (j * 64 + 63 > qw0) {
      int kb = j * 64 + 4 * half;
#pragma unroll
      for (int tt = 0; tt < 2; tt++)
#pragma unroll
        for (int r = 0; r < 16; r++) {
          int kk = kb + tt * 32 + (r & 3) + 8 * (r >> 2);
          if (kk > qg) sa[tt][r] = -3.0e38f;
        }
    }
    float mx = -3.0e38f;
#pragma unroll
    for (int r = 0; r < 16; r++) mx = fmaxf(mx, fmaxf(sa[0][r], sa[1][r]));
    mx = fmaxf(mx, __shfl_xor(mx, 32, 64));
    // defer-max: only rescale O when the running max actually grew (>8)
    if (!__all(mx <= m_i + 8.0f)) {
      float mn = fmaxf(m_i, mx);
      float al = exp2f((m_i - mn) * 1.44269504f);
      l_i *= al;
#pragma unroll
      for (int vt = 0; vt < 4; vt++)
#pragma unroll
        for (int r = 0; r < 16; r++) oacc[vt][r] *= al;
      m_i = mn;
    }
    float rs = 0.f;
#pragma unroll
    for (int tt = 0; tt < 2; tt++)
#pragma unroll
      for (int r = 0; r < 16; r++) {
        float p = exp2f((sa[tt][r] - m_i) * 1.44269504f);
        sa[tt][r] = p;
        rs += p;
      }
    rs += __shfl_xor(rs, 32, 64);
    l_i += rs;

    // ---- in-register P -> PV B-fragment via permlane32_swap (T12) ----
    // lane(q=l31, half h) owns P[k = 32tt + 8j + 4h + i] (j = r>>2, i = r&3).
    // pf[t=2tt+s][e] needs P[k = 32tt + 16s + 8h + e].
    bf16x8 pf[4];
#pragma unroll
    for (int tt = 0; tt < 2; tt++)
#pragma unroll
      for (int s = 0; s < 2; s++) {
        unsigned X0 = pk2(sa[tt][8 * s + 0], sa[tt][8 * s + 1]);
        unsigned X1 = pk2(sa[tt][8 * s + 2], sa[tt][8 * s + 3]);
        unsigned Y0 = pk2(sa[tt][8 * s + 4], sa[tt][8 * s + 5]);
        unsigned Y1 = pk2(sa[tt][8 * s + 6], sa[tt][8 * s + 7]);
        u32x2 r0 = __builtin_amdgcn_permlane32_swap(X0, Y0, false, false);
        u32x2 r1 = __builtin_amdgcn_permlane32_swap(X1, Y1, false, false);
        u32x4 w;
        w.x = r0.x;  // {X0 lo-lanes | Y0 lo-lanes}: elems 0,1
        w.y = r1.x;  // elems 2,3
        w.z = r0.y;  // {X0 hi-lanes | Y0 hi-lanes}: elems 4,5
        w.w = r1.y;  // elems 6,7
        pf[2 * tt + s] = __builtin_bit_cast(bf16x8, w);
      }

    __builtin_amdgcn_s_setprio(1);
#pragma unroll
    for (int t = 0; t < 4; t++) {
#pragma unroll
      for (int vt = 0; vt < 4; vt++) {
        bf16x8 vf = *(const bf16x8*)(vrd + vt * 32 * 64 + (((2 * t + half) ^ xr) << 3));
        oacc[vt] = __builtin_amdgcn_mfma_f32_32x32x16_bf16(vf, pf[t], oacc[vt], 0, 0, 0);
      }
    }
    __builtin_amdgcn_s_setprio(0);
  }
  float inv = 1.f / l_i;
  u16* orow = O + ((size_t)(b * T_ + qg)) * 2048 + h * 128 + 4 * half;
#pragma unroll
  for (int vt = 0; vt < 4; vt++)
#pragma unroll
    for (int qd = 0; qd < 4; qd++) {
      uint2 pk;
      pk.x = pk2(oacc[vt][qd * 4 + 0] * inv, oacc[vt][qd * 4 + 1] * inv);
      pk.y = pk2(oacc[vt][qd * 4 + 2] * inv, oacc[vt][qd * 4 + 3] * inv);
      *(uint2*)(orow + vt * 32 + qd * 8) = pk;
    }
}

extern "C" void kernel_launch(void* const* d_in, const int* in_sizes, int n_in,
                              void* d_out, int out_size, void* d_ws, size_t ws_size,
                              hipStream_t stream) {
  const float* x    = (const float*)d_in[0];
  const float* fcos = (const float*)d_in[1];
  const float* fsin = (const float*)d_in[2];
  const float* wqd  = (const float*)d_in[3];
  const float* qnw  = (const float*)d_in[4];
  const float* wqun = (const float*)d_in[5];
  const float* wqur = (const float*)d_in[6];
  const float* wkvd = (const float*)d_in[7];
  const float* kvnw = (const float*)d_in[8];
  const float* wkvu = (const float*)d_in[9];
  const float* qhnw = (const float*)d_in[10];
  const float* khnw = (const float*)d_in[11];
  const float* wwo  = (const float*)d_in[12];
  float* out = (float*)d_out;
  char* ws = (char*)d_ws;

  size_t off = 0;
  auto alloc = [&](size_t elems) -> u16* {
    u16* p = (u16*)(ws + off);
    off += ((elems * 2 + 255) & ~(size_t)255);
    return p;
  };
  u16* x16   = alloc(4096ull * 2048);
  u16* bqkvd = alloc(2176ull * 2048);  // fused q_down(1536) + kv_down(640)
  u16* bqu   = alloc(3072ull * 1536);  // merged q_up
  u16* bkvu  = alloc(4096ull * 512);
  u16* bwo   = alloc(2048ull * 2048);
  u16* cqkv  = alloc(4096ull * 2176);  // fused down-proj output
  u16* cq    = alloc(4096ull * 1536);
  u16* qnr   = alloc(4096ull * 3072);
  u16* ckv   = alloc(4096ull * 512);
  u16* kvu   = alloc(4096ull * 4096);
  u16* qp    = alloc(32ull * 2048 * 192);
  u16* kp    = alloc(32ull * 2048 * 192);
  u16* vp    = alloc(32ull * 2048 * 128);
  u16* ao    = alloc(4096ull * 2048);
  if (ws_size < off) return;

  cast_f32_bf16<<<8192, 256, 0, stream>>>(x, x16, 4096 * 2048);

  // six weight transposes, one dispatch
  CTSegs S;
  S.in[0] = wqd;  S.out[0] = bqkvd;                 S.R[0] = 2048; S.C[0] = 1536; S.gx[0] = 48;
  S.in[1] = wkvd; S.out[1] = bqkvd + 1536ull * 2048; S.R[1] = 2048; S.C[1] = 576;  S.gx[1] = 20;
  S.in[2] = wqun; S.out[2] = bqu;                   S.R[2] = 1536; S.C[2] = 2048; S.gx[2] = 64;
  S.in[3] = wqur; S.out[3] = bqu + 2048ull * 1536;  S.R[3] = 1536; S.C[3] = 1024; S.gx[3] = 32;
  S.in[4] = wkvu; S.out[4] = bkvu;                  S.R[4] = 512;  S.C[4] = 4096; S.gx[4] = 128;
  S.in[5] = wwo;  S.out[5] = bwo;                   S.R[5] = 2048; S.C[5] = 2048; S.gx[5] = 64;
  int tot = 0;
  int gy[6] = {64, 64, 48, 48, 16, 64};
  for (int k = 0; k < 6; k++) { S.start[k] = tot; tot += S.gx[k] * gy[k]; }
  castT_multi<<<tot, 256, 0, stream>>>(S);

  gemm_bt<<<dim3(17, 32), 256, 0, stream>>>(x16, bqkvd, cqkv, 4096, 2176, 2048, 0);
  rmsnorm_dual<<<8192, 256, 0, stream>>>(cqkv, cq, qnw, ckv, kvnw);
  // q_up (K=1536) and kv_up (K=512) fused: long-K z=0 first, short-K backfills
  gemm_bt2<<<dim3(32, 32, 2), 256, 0, stream>>>(cq, bqu, qnr, 3072, 1536, 24,
                                                ckv, bkvu, kvu, 4096, 512, 32);
  pack_dual<<<17408, 256, 0, stream>>>(qnr, qhnw, fcos, fsin, qp,
                                       kvu, cqkv + 1536, khnw, kp, vp);
  attn_kernel<<<512, 256, 0, stream>>>(qp, kp, vp, ao);
  gemm_bt<<<dim3(16, 32), 256, 0, stream>>>(ao, bwo, out, 4096, 2048, 2048, 1);
}